// Round 1
// baseline (569.294 us; speedup 1.0000x reference)
//
#include <hip/hip_runtime.h>
#include <hip/hip_bf16.h>

#define B_  16
#define S_  1024
#define H_  768
#define NH_ 12
#define HD_ 64
#define BS_ (B_*S_)   // 16384

typedef __bf16 bfx8 __attribute__((ext_vector_type(8)));
typedef __bf16 bfx4 __attribute__((ext_vector_type(4)));
typedef float  f32x4 __attribute__((ext_vector_type(4)));

#define MFMA(a,b,c) __builtin_amdgcn_mfma_f32_16x16x32_bf16(a,b,c,0,0,0)

// ---------------------------------------------------------------------------
// QKV projection: C[m,n] = sum_k A[m,k]*W[n,k] + bias[n]
// A = hidden fp32 (BS x 768), W fp32 (768 x 768) torch-Linear layout (out,in).
// Store bf16 permuted to (B, NH, S, D) so attention tiles are contiguous.
// 128x128 tile, BK=64, 4 waves in 2x2, each wave 4x4 of 16x16 mfma tiles.
// ---------------------------------------------------------------------------
__global__ __launch_bounds__(256) void qkv_gemm(
    const float* __restrict__ hidden,
    const float* __restrict__ qw, const float* __restrict__ qb,
    const float* __restrict__ kw, const float* __restrict__ kb,
    const float* __restrict__ vw, const float* __restrict__ vb,
    __bf16* __restrict__ qo, __bf16* __restrict__ ko, __bf16* __restrict__ vo)
{
    const float* W; const float* bias; __bf16* out;
    if (blockIdx.z == 0)      { W = qw; bias = qb; out = qo; }
    else if (blockIdx.z == 1) { W = kw; bias = kb; out = ko; }
    else                      { W = vw; bias = vb; out = vo; }

    __shared__ __bf16 As[128*72];   // row stride 72 bf16 = 144B (16B aligned, ~2-way banks)
    __shared__ __bf16 Bs[128*72];

    const int tid  = threadIdx.x;
    const int lane = tid & 63, wid = tid >> 6;
    const int quad = lane >> 4, l16 = lane & 15;
    const int m0 = blockIdx.x * 128, n0 = blockIdx.y * 128;
    const int wm = (wid >> 1) * 64, wn = (wid & 1) * 64;

    f32x4 acc[4][4];
    #pragma unroll
    for (int i = 0; i < 4; ++i)
        #pragma unroll
        for (int j = 0; j < 4; ++j)
            #pragma unroll
            for (int r = 0; r < 4; ++r) acc[i][j][r] = 0.0f;

    const int srow = tid >> 4;        // 16 rows/pass
    const int sc4  = (tid & 15) * 4;  // float4 column

    for (int kt = 0; kt < 12; ++kt) {
        __syncthreads();
        const int k0 = kt * 64;
        #pragma unroll
        for (int p = 0; p < 8; ++p) {
            const int row = p * 16 + srow;
            f32x4 av = *(const f32x4*)(hidden + (long)(m0 + row) * H_ + k0 + sc4);
            f32x4 bv = *(const f32x4*)(W      + (long)(n0 + row) * H_ + k0 + sc4);
            bfx4 a4, b4;
            #pragma unroll
            for (int j = 0; j < 4; ++j) { a4[j] = (__bf16)av[j]; b4[j] = (__bf16)bv[j]; }
            *(bfx4*)(As + row * 72 + sc4) = a4;
            *(bfx4*)(Bs + row * 72 + sc4) = b4;
        }
        __syncthreads();
        #pragma unroll
        for (int ks = 0; ks < 2; ++ks) {
            const int koff = ks * 32 + quad * 8;
            bfx8 af[4], bfr[4];
            #pragma unroll
            for (int t = 0; t < 4; ++t) {
                af[t]  = *(const bfx8*)(As + (wm + t * 16 + l16) * 72 + koff);
                bfr[t] = *(const bfx8*)(Bs + (wn + t * 16 + l16) * 72 + koff);
            }
            #pragma unroll
            for (int mt = 0; mt < 4; ++mt)
                #pragma unroll
                for (int nt = 0; nt < 4; ++nt)
                    acc[mt][nt] = MFMA(af[mt], bfr[nt], acc[mt][nt]);
        }
    }

    // epilogue: C/D layout col = lane&15, row = quad*4 + reg
    #pragma unroll
    for (int nt = 0; nt < 4; ++nt) {
        const int n = n0 + wn + nt * 16 + l16;
        const float bv = bias[n];
        const int h = n >> 6, d = n & 63;
        #pragma unroll
        for (int mt = 0; mt < 4; ++mt) {
            #pragma unroll
            for (int r = 0; r < 4; ++r) {
                const int m = m0 + wm + mt * 16 + quad * 4 + r;
                const int b = m >> 10, s = m & 1023;
                out[(((long)(b * NH_ + h) << 10) + s) * HD_ + d] = (__bf16)(acc[mt][nt][r] + bv);
            }
        }
    }
}

// ---------------------------------------------------------------------------
// Flash-style attention: block per (qt, h, b); 4 waves, wave owns 16 q rows.
// Online softmax over 16 k-tiles of 64 keys. Q,K,V in (B,NH,S,D) bf16.
// ---------------------------------------------------------------------------
__global__ __launch_bounds__(256) void attn_kernel(
    const __bf16* __restrict__ q, const __bf16* __restrict__ k,
    const __bf16* __restrict__ v, const float* __restrict__ mask,
    __bf16* __restrict__ ctx)
{
    __shared__ __bf16 Ks[64 * 72];      // [key][d]
    __shared__ __bf16 Vs[64 * 72];      // transposed: [d][key]
    __shared__ __bf16 Ps[4][16 * 72];   // per-wave P round-trip (C-layout -> A-layout)

    const int tid  = threadIdx.x;
    const int lane = tid & 63, wid = tid >> 6;
    const int quad = lane >> 4, l16 = lane & 15;
    const int qt = blockIdx.x, h = blockIdx.y, b = blockIdx.z;

    const long base = ((long)(b * NH_ + h)) << 16;   // * S_ * HD_
    const __bf16* qh = q + base;
    const __bf16* kh = k + base;
    const __bf16* vh = v + base;
    const float*  mb = mask + b * S_;

    // Q A-fragments: A[m=lane&15][k=quad*8+j], two k-steps of 32
    bfx8 qf[2];
    {
        const int qrow = qt * 64 + wid * 16 + l16;
        qf[0] = *(const bfx8*)(qh + qrow * 64 + 0 * 32 + quad * 8);
        qf[1] = *(const bfx8*)(qh + qrow * 64 + 1 * 32 + quad * 8);
    }

    f32x4 o[4]; float mrow[4], lrow[4];
    #pragma unroll
    for (int i = 0; i < 4; ++i) {
        #pragma unroll
        for (int r = 0; r < 4; ++r) o[i][r] = 0.0f;
        mrow[i] = -1e30f; lrow[i] = 0.0f;
    }

    const int srow2 = tid >> 3;        // 32 rows/pass
    const int sc8   = (tid & 7) * 8;   // 8-elem column group

    for (int kt = 0; kt < 16; ++kt) {
        __syncthreads();
        #pragma unroll
        for (int p = 0; p < 2; ++p) {
            const int row = p * 32 + srow2;
            bfx8 kv = *(const bfx8*)(kh + (kt * 64 + row) * 64 + sc8);
            *(bfx8*)(Ks + row * 72 + sc8) = kv;
            bfx8 vv = *(const bfx8*)(vh + (kt * 64 + row) * 64 + sc8);
            #pragma unroll
            for (int j = 0; j < 8; ++j) Vs[(sc8 + j) * 72 + row] = vv[j];
        }
        __syncthreads();

        // scores: S = Q * K^T  (B-op frag = K[key=lane&15][d=quad*8+j], K-contig)
        f32x4 scv[4];
        #pragma unroll
        for (int nt = 0; nt < 4; ++nt)
            #pragma unroll
            for (int r = 0; r < 4; ++r) scv[nt][r] = 0.0f;
        #pragma unroll
        for (int ks = 0; ks < 2; ++ks) {
            const int koff = ks * 32 + quad * 8;
            #pragma unroll
            for (int nt = 0; nt < 4; ++nt) {
                bfx8 kf = *(const bfx8*)(Ks + (nt * 16 + l16) * 72 + koff);
                scv[nt] = MFMA(qf[ks], kf, scv[nt]);
            }
        }
        // scale + additive mask
        float tmax[4] = {-1e30f, -1e30f, -1e30f, -1e30f};
        #pragma unroll
        for (int nt = 0; nt < 4; ++nt) {
            const float mk = mb[kt * 64 + nt * 16 + l16];
            #pragma unroll
            for (int r = 0; r < 4; ++r) {
                scv[nt][r] = scv[nt][r] * 0.125f + mk;
                tmax[r] = fmaxf(tmax[r], scv[nt][r]);
            }
        }
        // row max across the 16 lanes of the quad (cols)
        #pragma unroll
        for (int r = 0; r < 4; ++r) {
            tmax[r] = fmaxf(tmax[r], __shfl_xor(tmax[r], 1));
            tmax[r] = fmaxf(tmax[r], __shfl_xor(tmax[r], 2));
            tmax[r] = fmaxf(tmax[r], __shfl_xor(tmax[r], 4));
            tmax[r] = fmaxf(tmax[r], __shfl_xor(tmax[r], 8));
        }
        float alpha[4], lsum[4];
        #pragma unroll
        for (int r = 0; r < 4; ++r) {
            const float mnew = fmaxf(mrow[r], tmax[r]);
            alpha[r] = __expf(mrow[r] - mnew);
            mrow[r] = mnew;
            lsum[r] = 0.0f;
        }
        #pragma unroll
        for (int nt = 0; nt < 4; ++nt)
            #pragma unroll
            for (int r = 0; r < 4; ++r) {
                const float p_ = __expf(scv[nt][r] - mrow[r]);
                scv[nt][r] = p_;
                lsum[r] += p_;
            }
        #pragma unroll
        for (int r = 0; r < 4; ++r) {
            lsum[r] += __shfl_xor(lsum[r], 1);
            lsum[r] += __shfl_xor(lsum[r], 2);
            lsum[r] += __shfl_xor(lsum[r], 4);
            lsum[r] += __shfl_xor(lsum[r], 8);
            lrow[r] = lrow[r] * alpha[r] + lsum[r];
        }
        #pragma unroll
        for (int nt = 0; nt < 4; ++nt)
            #pragma unroll
            for (int r = 0; r < 4; ++r) o[nt][r] *= alpha[r];

        // P: C-layout -> LDS -> A-layout
        #pragma unroll
        for (int nt = 0; nt < 4; ++nt)
            #pragma unroll
            for (int r = 0; r < 4; ++r)
                Ps[wid][(quad * 4 + r) * 72 + nt * 16 + l16] = (__bf16)scv[nt][r];
        __syncthreads();

        // O += P * V   (B-op frag = Vs[d=lane&15][key=quad*8+j], K-contig via transpose)
        #pragma unroll
        for (int ks = 0; ks < 2; ++ks) {
            const int koff = ks * 32 + quad * 8;
            bfx8 pf = *(const bfx8*)(&Ps[wid][l16 * 72 + koff]);
            #pragma unroll
            for (int nt = 0; nt < 4; ++nt) {
                bfx8 vf = *(const bfx8*)(Vs + (nt * 16 + l16) * 72 + koff);
                o[nt] = MFMA(pf, vf, o[nt]);
            }
        }
    }

    float inv[4];
    #pragma unroll
    for (int r = 0; r < 4; ++r) inv[r] = 1.0f / lrow[r];
    #pragma unroll
    for (int nt = 0; nt < 4; ++nt)
        #pragma unroll
        for (int r = 0; r < 4; ++r) {
            const int qrow = qt * 64 + wid * 16 + quad * 4 + r;
            ctx[((long)(b << 10) + qrow) * H_ + h * 64 + nt * 16 + l16] =
                (__bf16)(o[nt][r] * inv[r]);
        }
}

// ---------------------------------------------------------------------------
// Output projection + residual: xres[m,n] = sum_k ctx[m,k]*ow[n,k] + ob[n] + hidden[m,n]
// ---------------------------------------------------------------------------
__global__ __launch_bounds__(256) void out_gemm(
    const __bf16* __restrict__ ctx, const float* __restrict__ ow,
    const float* __restrict__ ob, const float* __restrict__ hidden,
    float* __restrict__ xres)
{
    __shared__ __bf16 As[128*72];
    __shared__ __bf16 Bs[128*72];

    const int tid  = threadIdx.x;
    const int lane = tid & 63, wid = tid >> 6;
    const int quad = lane >> 4, l16 = lane & 15;
    const int m0 = blockIdx.x * 128, n0 = blockIdx.y * 128;
    const int wm = (wid >> 1) * 64, wn = (wid & 1) * 64;

    f32x4 acc[4][4];
    #pragma unroll
    for (int i = 0; i < 4; ++i)
        #pragma unroll
        for (int j = 0; j < 4; ++j)
            #pragma unroll
            for (int r = 0; r < 4; ++r) acc[i][j][r] = 0.0f;

    const int srowA = tid >> 3;  const int sc8 = (tid & 7) * 8;
    const int srowB = tid >> 4;  const int sc4 = (tid & 15) * 4;

    for (int kt = 0; kt < 12; ++kt) {
        __syncthreads();
        const int k0 = kt * 64;
        #pragma unroll
        for (int p = 0; p < 4; ++p) {
            const int row = p * 32 + srowA;
            *(bfx8*)(As + row * 72 + sc8) =
                *(const bfx8*)(ctx + (long)(m0 + row) * H_ + k0 + sc8);
        }
        #pragma unroll
        for (int p = 0; p < 8; ++p) {
            const int row = p * 16 + srowB;
            f32x4 bv = *(const f32x4*)(ow + (long)(n0 + row) * H_ + k0 + sc4);
            bfx4 b4;
            #pragma unroll
            for (int j = 0; j < 4; ++j) b4[j] = (__bf16)bv[j];
            *(bfx4*)(Bs + row * 72 + sc4) = b4;
        }
        __syncthreads();
        #pragma unroll
        for (int ks = 0; ks < 2; ++ks) {
            const int koff = ks * 32 + quad * 8;
            bfx8 af[4], bfr[4];
            #pragma unroll
            for (int t = 0; t < 4; ++t) {
                af[t]  = *(const bfx8*)(As + (wm + t * 16 + l16) * 72 + koff);
                bfr[t] = *(const bfx8*)(Bs + (wn + t * 16 + l16) * 72 + koff);
            }
            #pragma unroll
            for (int mt = 0; mt < 4; ++mt)
                #pragma unroll
                for (int nt = 0; nt < 4; ++nt)
                    acc[mt][nt] = MFMA(af[mt], bfr[nt], acc[mt][nt]);
        }
    }

    #pragma unroll
    for (int nt = 0; nt < 4; ++nt) {
        const int n = n0 + wn + nt * 16 + l16;
        const float bv = ob[n];
        #pragma unroll
        for (int mt = 0; mt < 4; ++mt) {
            #pragma unroll
            for (int r = 0; r < 4; ++r) {
                const int m = m0 + wm + mt * 16 + quad * 4 + r;
                const long idx = (long)m * H_ + n;
                xres[idx] = acc[mt][nt][r] + bv + hidden[idx];
            }
        }
    }
}

// ---------------------------------------------------------------------------
// LayerNorm over H=768, wave per row (12 floats/lane), fp32 out.
// ---------------------------------------------------------------------------
__global__ __launch_bounds__(256) void ln_kernel(
    const float* __restrict__ xres, const float* __restrict__ gamma,
    const float* __restrict__ beta, float* __restrict__ out)
{
    const int tid = threadIdx.x, lane = tid & 63, wid = tid >> 6;
    const long row = (long)blockIdx.x * 4 + wid;
    const float* xr = xres + row * H_;

    f32x4 xv[3];
    float sum = 0.0f, sumsq = 0.0f;
    #pragma unroll
    for (int c = 0; c < 3; ++c) {
        xv[c] = *(const f32x4*)(xr + c * 256 + lane * 4);
        #pragma unroll
        for (int j = 0; j < 4; ++j) { sum += xv[c][j]; sumsq += xv[c][j] * xv[c][j]; }
    }
    #pragma unroll
    for (int off = 1; off < 64; off <<= 1) {
        sum   += __shfl_xor(sum, off);
        sumsq += __shfl_xor(sumsq, off);
    }
    const float mean = sum * (1.0f / 768.0f);
    const float var  = sumsq * (1.0f / 768.0f) - mean * mean;
    const float rstd = rsqrtf(var + 1e-12f);

    float* orow = out + row * H_;
    #pragma unroll
    for (int c = 0; c < 3; ++c) {
        f32x4 g  = *(const f32x4*)(gamma + c * 256 + lane * 4);
        f32x4 bt = *(const f32x4*)(beta  + c * 256 + lane * 4);
        f32x4 ov;
        #pragma unroll
        for (int j = 0; j < 4; ++j) ov[j] = (xv[c][j] - mean) * rstd * g[j] + bt[j];
        *(f32x4*)(orow + c * 256 + lane * 4) = ov;
    }
}

extern "C" void kernel_launch(void* const* d_in, const int* in_sizes, int n_in,
                              void* d_out, int out_size, void* d_ws, size_t ws_size,
                              hipStream_t stream)
{
    const float* hidden = (const float*)d_in[0];
    const float* mask   = (const float*)d_in[1];
    const float* qw = (const float*)d_in[2];
    const float* qb = (const float*)d_in[3];
    const float* kw = (const float*)d_in[4];
    const float* kb = (const float*)d_in[5];
    const float* vw = (const float*)d_in[6];
    const float* vb = (const float*)d_in[7];
    const float* ow = (const float*)d_in[8];
    const float* ob = (const float*)d_in[9];
    const float* gamma = (const float*)d_in[10];
    const float* beta  = (const float*)d_in[11];
    float* out = (float*)d_out;

    char* ws = (char*)d_ws;
    const size_t SZ = (size_t)BS_ * H_;          // 12,582,912 elements
    __bf16* qws = (__bf16*)(ws);                 // 24MB  (B,NH,S,D)
    __bf16* kws = (__bf16*)(ws + SZ * 2);        // 24MB
    __bf16* vws = (__bf16*)(ws + SZ * 4);        // 24MB
    __bf16* cws = (__bf16*)(ws + SZ * 6);        // 24MB  (B,S,H)
    float*  xres = (float*)(ws);                 // 48MB fp32, aliases q+k (dead after attn)

    qkv_gemm<<<dim3(128, 6, 3), 256, 0, stream>>>(hidden, qw, qb, kw, kb, vw, vb,
                                                  qws, kws, vws);
    attn_kernel<<<dim3(16, 12, 16), 256, 0, stream>>>(qws, kws, vws, mask, cws);
    out_gemm<<<dim3(128, 6), 256, 0, stream>>>(cws, ow, ob, hidden, xres);
    ln_kernel<<<dim3(4096), 256, 0, stream>>>(xres, gamma, beta, out);
}

// Round 2
// 421.971 us; speedup vs baseline: 1.3491x; 1.3491x over previous
//
#include <hip/hip_runtime.h>
#include <hip/hip_bf16.h>

#define B_  16
#define S_  1024
#define H_  768
#define NH_ 12
#define HD_ 64
#define BS_ (B_*S_)   // 16384

typedef __bf16 bfx8 __attribute__((ext_vector_type(8)));
typedef __bf16 bfx4 __attribute__((ext_vector_type(4)));
typedef float  f32x4 __attribute__((ext_vector_type(4)));

#define MFMA(a,b,c) __builtin_amdgcn_mfma_f32_16x16x32_bf16(a,b,c,0,0,0)

__device__ __forceinline__ float fast_exp2(float x) {
#if __has_builtin(__builtin_amdgcn_exp2f)
    return __builtin_amdgcn_exp2f(x);
#else
    return exp2f(x);
#endif
}

#define LOG2E 1.4426950408889634f
#define C1    (0.125f * LOG2E)     // score scale folded with log2(e)
#define SMAX  12.0f                // static softmax offset (exp2 domain)

// ---------------------------------------------------------------------------
// QKV projection: C[m,n] = sum_k A[m,k]*W[n,k] + bias[n]
// Q,K stored (B,NH,S,D) bf16. V stored TRANSPOSED (B,NH,D,S) bf16 so the
// attention kernel can stage V^T tiles with pure vector loads (no LDS
// transpose -> no 16-way bank conflicts).
// ---------------------------------------------------------------------------
__global__ __launch_bounds__(256) void qkv_gemm(
    const float* __restrict__ hidden,
    const float* __restrict__ qw, const float* __restrict__ qb,
    const float* __restrict__ kw, const float* __restrict__ kb,
    const float* __restrict__ vw, const float* __restrict__ vb,
    __bf16* __restrict__ qo, __bf16* __restrict__ ko, __bf16* __restrict__ vto)
{
    const float* W; const float* bias;
    if (blockIdx.z == 0)      { W = qw; bias = qb; }
    else if (blockIdx.z == 1) { W = kw; bias = kb; }
    else                      { W = vw; bias = vb; }

    __shared__ __bf16 As[128*72];
    __shared__ __bf16 Bs[128*72];

    const int tid  = threadIdx.x;
    const int lane = tid & 63, wid = tid >> 6;
    const int quad = lane >> 4, l16 = lane & 15;
    const int m0 = blockIdx.x * 128, n0 = blockIdx.y * 128;
    const int wm = (wid >> 1) * 64, wn = (wid & 1) * 64;

    f32x4 acc[4][4];
    #pragma unroll
    for (int i = 0; i < 4; ++i)
        #pragma unroll
        for (int j = 0; j < 4; ++j)
            #pragma unroll
            for (int r = 0; r < 4; ++r) acc[i][j][r] = 0.0f;

    const int srow = tid >> 4;        // 16 rows/pass
    const int sc4  = (tid & 15) * 4;  // float4 column

    for (int kt = 0; kt < 12; ++kt) {
        __syncthreads();
        const int k0 = kt * 64;
        #pragma unroll
        for (int p = 0; p < 8; ++p) {
            const int row = p * 16 + srow;
            f32x4 av = *(const f32x4*)(hidden + (long)(m0 + row) * H_ + k0 + sc4);
            f32x4 bv = *(const f32x4*)(W      + (long)(n0 + row) * H_ + k0 + sc4);
            bfx4 a4, b4;
            #pragma unroll
            for (int j = 0; j < 4; ++j) { a4[j] = (__bf16)av[j]; b4[j] = (__bf16)bv[j]; }
            *(bfx4*)(As + row * 72 + sc4) = a4;
            *(bfx4*)(Bs + row * 72 + sc4) = b4;
        }
        __syncthreads();
        #pragma unroll
        for (int ks = 0; ks < 2; ++ks) {
            const int koff = ks * 32 + quad * 8;
            bfx8 af[4], bfr[4];
            #pragma unroll
            for (int t = 0; t < 4; ++t) {
                af[t]  = *(const bfx8*)(As + (wm + t * 16 + l16) * 72 + koff);
                bfr[t] = *(const bfx8*)(Bs + (wn + t * 16 + l16) * 72 + koff);
            }
            #pragma unroll
            for (int mt = 0; mt < 4; ++mt)
                #pragma unroll
                for (int nt = 0; nt < 4; ++nt)
                    acc[mt][nt] = MFMA(af[mt], bfr[nt], acc[mt][nt]);
        }
    }

    // epilogue: C/D layout col = lane&15 (n), row = quad*4 + reg (m)
    if (blockIdx.z != 2) {
        __bf16* out = (blockIdx.z == 0) ? qo : ko;
        #pragma unroll
        for (int nt = 0; nt < 4; ++nt) {
            const int n = n0 + wn + nt * 16 + l16;
            const float bv = bias[n];
            const int h = n >> 6, d = n & 63;
            #pragma unroll
            for (int mt = 0; mt < 4; ++mt) {
                #pragma unroll
                for (int r = 0; r < 4; ++r) {
                    const int m = m0 + wm + mt * 16 + quad * 4 + r;
                    const int b = m >> 10, s = m & 1023;
                    out[(((long)(b * NH_ + h) << 10) + s) * HD_ + d] =
                        (__bf16)(acc[mt][nt][r] + bv);
                }
            }
        }
    } else {
        // V transposed: vto[((b*NH+h)*64 + d)*1024 + s], r-contiguous in s
        #pragma unroll
        for (int nt = 0; nt < 4; ++nt) {
            const int n = n0 + wn + nt * 16 + l16;
            const float bv = bias[n];
            const int h = n >> 6, d = n & 63;
            #pragma unroll
            for (int mt = 0; mt < 4; ++mt) {
                const int m = m0 + wm + mt * 16 + quad * 4;
                const int b = m >> 10, s = m & 1023;
                bfx4 pk;
                #pragma unroll
                for (int r = 0; r < 4; ++r) pk[r] = (__bf16)(acc[mt][nt][r] + bv);
                *(bfx4*)(vto + (((long)(b * NH_ + h) * HD_ + d) << 10) + s) = pk;
            }
        }
    }
}

// ---------------------------------------------------------------------------
// Attention, S^T formulation. Block = 512 threads = 8 waves, each wave owns
// 32 q-rows (256 q-rows per block -> 4x K/V reuse vs 64-row blocks).
// S^T = K*Q^T (mfma A=K, B=Q) so C rows are KEYS: the 4 accumulator regs are
// key-contiguous -> P written into Ps[q][key] with packed ds_write_b64, read
// back as vector b128 B-frags for O^T = V^T*P^T. Per-wave Ps => no barrier
// between QK^T and PV. Static-max softmax in exp2 domain (offset folded into
// the pre-scaled mask in LDS); l reduced once at the end.
// ---------------------------------------------------------------------------
__global__ __launch_bounds__(512, 4) void attn_kernel(
    const __bf16* __restrict__ q, const __bf16* __restrict__ k,
    const __bf16* __restrict__ vT, const float* __restrict__ mask,
    __bf16* __restrict__ ctx)
{
    __shared__ __bf16 Ks[64 * 72];      // [key][d]
    __shared__ __bf16 Vs[64 * 72];      // [d][key]  (V^T tile, loaded directly)
    __shared__ __bf16 Ps[8][32 * 72];   // per-wave [q][key]
    __shared__ float  Ms[1024];         // mask*log2e - SMAX

    const int tid  = threadIdx.x;
    const int lane = tid & 63, wid = tid >> 6;
    const int quad = lane >> 4, l16 = lane & 15;
    const int qc = blockIdx.x, h = blockIdx.y, b = blockIdx.z;

    const long base = ((long)(b * NH_ + h)) << 16;   // * S_ * HD_
    const __bf16* qh = q  + base;
    const __bf16* kh = k  + base;
    const __bf16* vh = vT + base;
    const float*  mb = mask + b * S_;

    Ms[tid]       = mb[tid]       * LOG2E - SMAX;
    Ms[tid + 512] = mb[tid + 512] * LOG2E - SMAX;

    // Q B-frags: B[n=q=l16][k=d=quad*8+j], per wave 2 q-tiles x 2 k-steps
    const int qrow_base = qc * 256 + wid * 32;
    bfx8 qf[2][2];
    #pragma unroll
    for (int nt = 0; nt < 2; ++nt)
        #pragma unroll
        for (int ks = 0; ks < 2; ++ks)
            qf[nt][ks] = *(const bfx8*)(qh + (qrow_base + nt * 16 + l16) * HD_ +
                                        ks * 32 + quad * 8);

    f32x4 o[4][2];     // O^T tiles: [d-tile][q-tile], row=d, col=q
    f32x4 lacc[2];
    #pragma unroll
    for (int mt = 0; mt < 4; ++mt)
        #pragma unroll
        for (int nt = 0; nt < 2; ++nt)
            #pragma unroll
            for (int r = 0; r < 4; ++r) o[mt][nt][r] = 0.0f;
    #pragma unroll
    for (int nt = 0; nt < 2; ++nt)
        #pragma unroll
        for (int r = 0; r < 4; ++r) lacc[nt][r] = 0.0f;

    const int srow = tid >> 3;        // 64 rows over 512 threads
    const int scol = (tid & 7) * 8;

    for (int kt = 0; kt < 16; ++kt) {
        __syncthreads();
        *(bfx8*)(Ks + srow * 72 + scol) =
            *(const bfx8*)(kh + (kt * 64 + srow) * HD_ + scol);
        *(bfx8*)(Vs + srow * 72 + scol) =
            *(const bfx8*)(vh + srow * S_ + kt * 64 + scol);
        __syncthreads();

        // S^T then softmax per key-tile t (keeps sc lifetime short)
        #pragma unroll
        for (int t = 0; t < 4; ++t) {
            f32x4 sc[2];
            #pragma unroll
            for (int nt = 0; nt < 2; ++nt)
                #pragma unroll
                for (int r = 0; r < 4; ++r) sc[nt][r] = 0.0f;
            #pragma unroll
            for (int ks = 0; ks < 2; ++ks) {
                bfx8 kf = *(const bfx8*)(Ks + (t * 16 + l16) * 72 +
                                         ks * 32 + quad * 8);
                #pragma unroll
                for (int nt = 0; nt < 2; ++nt)
                    sc[nt] = MFMA(kf, qf[nt][ks], sc[nt]);
            }
            const f32x4 mv = *(const f32x4*)(&Ms[kt * 64 + t * 16 + quad * 4]);
            #pragma unroll
            for (int nt = 0; nt < 2; ++nt) {
                f32x4 p; bfx4 pb;
                #pragma unroll
                for (int r = 0; r < 4; ++r)
                    p[r] = fast_exp2(sc[nt][r] * C1 + mv[r]);
                lacc[nt] += p;
                #pragma unroll
                for (int r = 0; r < 4; ++r) pb[r] = (__bf16)p[r];
                *(bfx4*)(&Ps[wid][(nt * 16 + l16) * 72 + t * 16 + quad * 4]) = pb;
            }
        }

        // O^T += V^T * P^T (A = Vs[d][key], B = Ps[q][key]); per-wave Ps,
        // same-wave ds ordering -> no barrier needed here.
        #pragma unroll
        for (int ks = 0; ks < 2; ++ks) {
            const int koff = ks * 32 + quad * 8;
            bfx8 pf[2];
            #pragma unroll
            for (int nt = 0; nt < 2; ++nt)
                pf[nt] = *(const bfx8*)(&Ps[wid][(nt * 16 + l16) * 72 + koff]);
            #pragma unroll
            for (int mt = 0; mt < 4; ++mt) {
                bfx8 vf = *(const bfx8*)(Vs + (mt * 16 + l16) * 72 + koff);
                #pragma unroll
                for (int nt = 0; nt < 2; ++nt)
                    o[mt][nt] = MFMA(vf, pf[nt], o[mt][nt]);
            }
        }
    }

    // l: per-lane horizontal sum, then reduce across the 4 quads
    float linv[2];
    #pragma unroll
    for (int nt = 0; nt < 2; ++nt) {
        float s = lacc[nt][0] + lacc[nt][1] + lacc[nt][2] + lacc[nt][3];
        s += __shfl_xor(s, 16);
        s += __shfl_xor(s, 32);
        linv[nt] = 1.0f / s;
    }

    // O^T C-layout: row=d=mt*16+quad*4+r, col=q=nt*16+l16 -> r-contig in d
    #pragma unroll
    for (int nt = 0; nt < 2; ++nt) {
        #pragma unroll
        for (int mt = 0; mt < 4; ++mt) {
            bfx4 ov;
            #pragma unroll
            for (int r = 0; r < 4; ++r)
                ov[r] = (__bf16)(o[mt][nt][r] * linv[nt]);
            const int qrow = qrow_base + nt * 16 + l16;
            *(bfx4*)(ctx + ((long)(b << 10) + qrow) * H_ + h * HD_ +
                     mt * 16 + quad * 4) = ov;
        }
    }
}

// ---------------------------------------------------------------------------
// Output projection + residual
// ---------------------------------------------------------------------------
__global__ __launch_bounds__(256) void out_gemm(
    const __bf16* __restrict__ ctx, const float* __restrict__ ow,
    const float* __restrict__ ob, const float* __restrict__ hidden,
    float* __restrict__ xres)
{
    __shared__ __bf16 As[128*72];
    __shared__ __bf16 Bs[128*72];

    const int tid  = threadIdx.x;
    const int lane = tid & 63, wid = tid >> 6;
    const int quad = lane >> 4, l16 = lane & 15;
    const int m0 = blockIdx.x * 128, n0 = blockIdx.y * 128;
    const int wm = (wid >> 1) * 64, wn = (wid & 1) * 64;

    f32x4 acc[4][4];
    #pragma unroll
    for (int i = 0; i < 4; ++i)
        #pragma unroll
        for (int j = 0; j < 4; ++j)
            #pragma unroll
            for (int r = 0; r < 4; ++r) acc[i][j][r] = 0.0f;

    const int srowA = tid >> 3;  const int sc8 = (tid & 7) * 8;
    const int srowB = tid >> 4;  const int sc4 = (tid & 15) * 4;

    for (int kt = 0; kt < 12; ++kt) {
        __syncthreads();
        const int k0 = kt * 64;
        #pragma unroll
        for (int p = 0; p < 4; ++p) {
            const int row = p * 32 + srowA;
            *(bfx8*)(As + row * 72 + sc8) =
                *(const bfx8*)(ctx + (long)(m0 + row) * H_ + k0 + sc8);
        }
        #pragma unroll
        for (int p = 0; p < 8; ++p) {
            const int row = p * 16 + srowB;
            f32x4 bv = *(const f32x4*)(ow + (long)(n0 + row) * H_ + k0 + sc4);
            bfx4 b4;
            #pragma unroll
            for (int j = 0; j < 4; ++j) b4[j] = (__bf16)bv[j];
            *(bfx4*)(Bs + row * 72 + sc4) = b4;
        }
        __syncthreads();
        #pragma unroll
        for (int ks = 0; ks < 2; ++ks) {
            const int koff = ks * 32 + quad * 8;
            bfx8 af[4], bfr[4];
            #pragma unroll
            for (int t = 0; t < 4; ++t) {
                af[t]  = *(const bfx8*)(As + (wm + t * 16 + l16) * 72 + koff);
                bfr[t] = *(const bfx8*)(Bs + (wn + t * 16 + l16) * 72 + koff);
            }
            #pragma unroll
            for (int mt = 0; mt < 4; ++mt)
                #pragma unroll
                for (int nt = 0; nt < 4; ++nt)
                    acc[mt][nt] = MFMA(af[mt], bfr[nt], acc[mt][nt]);
        }
    }

    #pragma unroll
    for (int nt = 0; nt < 4; ++nt) {
        const int n = n0 + wn + nt * 16 + l16;
        const float bv = ob[n];
        #pragma unroll
        for (int mt = 0; mt < 4; ++mt) {
            #pragma unroll
            for (int r = 0; r < 4; ++r) {
                const int m = m0 + wm + mt * 16 + quad * 4 + r;
                const long idx = (long)m * H_ + n;
                xres[idx] = acc[mt][nt][r] + bv + hidden[idx];
            }
        }
    }
}

// ---------------------------------------------------------------------------
// LayerNorm over H=768, wave per row
// ---------------------------------------------------------------------------
__global__ __launch_bounds__(256) void ln_kernel(
    const float* __restrict__ xres, const float* __restrict__ gamma,
    const float* __restrict__ beta, float* __restrict__ out)
{
    const int tid = threadIdx.x, lane = tid & 63, wid = tid >> 6;
    const long row = (long)blockIdx.x * 4 + wid;
    const float* xr = xres + row * H_;

    f32x4 xv[3];
    float sum = 0.0f, sumsq = 0.0f;
    #pragma unroll
    for (int c = 0; c < 3; ++c) {
        xv[c] = *(const f32x4*)(xr + c * 256 + lane * 4);
        #pragma unroll
        for (int j = 0; j < 4; ++j) { sum += xv[c][j]; sumsq += xv[c][j] * xv[c][j]; }
    }
    #pragma unroll
    for (int off = 1; off < 64; off <<= 1) {
        sum   += __shfl_xor(sum, off);
        sumsq += __shfl_xor(sumsq, off);
    }
    const float mean = sum * (1.0f / 768.0f);
    const float var  = sumsq * (1.0f / 768.0f) - mean * mean;
    const float rstd = rsqrtf(var + 1e-12f);

    float* orow = out + row * H_;
    #pragma unroll
    for (int c = 0; c < 3; ++c) {
        f32x4 g  = *(const f32x4*)(gamma + c * 256 + lane * 4);
        f32x4 bt = *(const f32x4*)(beta  + c * 256 + lane * 4);
        f32x4 ov;
        #pragma unroll
        for (int j = 0; j < 4; ++j) ov[j] = (xv[c][j] - mean) * rstd * g[j] + bt[j];
        *(f32x4*)(orow + c * 256 + lane * 4) = ov;
    }
}

extern "C" void kernel_launch(void* const* d_in, const int* in_sizes, int n_in,
                              void* d_out, int out_size, void* d_ws, size_t ws_size,
                              hipStream_t stream)
{
    const float* hidden = (const float*)d_in[0];
    const float* mask   = (const float*)d_in[1];
    const float* qw = (const float*)d_in[2];
    const float* qb = (const float*)d_in[3];
    const float* kw = (const float*)d_in[4];
    const float* kb = (const float*)d_in[5];
    const float* vw = (const float*)d_in[6];
    const float* vb = (const float*)d_in[7];
    const float* ow = (const float*)d_in[8];
    const float* ob = (const float*)d_in[9];
    const float* gamma = (const float*)d_in[10];
    const float* beta  = (const float*)d_in[11];
    float* out = (float*)d_out;

    char* ws = (char*)d_ws;
    const size_t SZ = (size_t)BS_ * H_;          // 12,582,912 elements
    __bf16* qws = (__bf16*)(ws);                 // 24MB  (B,NH,S,D)
    __bf16* kws = (__bf16*)(ws + SZ * 2);        // 24MB  (B,NH,S,D)
    __bf16* vtws = (__bf16*)(ws + SZ * 4);       // 24MB  (B,NH,D,S)  V^T
    __bf16* cws = (__bf16*)(ws + SZ * 6);        // 24MB  (B,S,H)
    float*  xres = (float*)(ws);                 // 48MB fp32, aliases q+k (dead after attn)

    qkv_gemm<<<dim3(128, 6, 3), 256, 0, stream>>>(hidden, qw, qb, kw, kb, vw, vb,
                                                  qws, kws, vtws);
    attn_kernel<<<dim3(4, 12, 16), 512, 0, stream>>>(qws, kws, vtws, mask, cws);
    out_gemm<<<dim3(128, 6), 256, 0, stream>>>(cws, ow, ob, hidden, xres);
    ln_kernel<<<dim3(4096), 256, 0, stream>>>(xres, gamma, beta, out);
}

// Round 3
// 418.672 us; speedup vs baseline: 1.3598x; 1.0079x over previous
//
#include <hip/hip_runtime.h>
#include <hip/hip_bf16.h>

#define B_  16
#define S_  1024
#define H_  768
#define NH_ 12
#define HD_ 64
#define BS_ (B_*S_)   // 16384
#define WROWS_ 589824 // 768*768 per weight matrix

typedef __bf16 bfx8 __attribute__((ext_vector_type(8)));
typedef __bf16 bfx4 __attribute__((ext_vector_type(4)));
typedef float  f32x4 __attribute__((ext_vector_type(4)));

#define MFMA(a,b,c) __builtin_amdgcn_mfma_f32_16x16x32_bf16(a,b,c,0,0,0)

__device__ __forceinline__ float fast_exp2(float x) {
#if __has_builtin(__builtin_amdgcn_exp2f)
    return __builtin_amdgcn_exp2f(x);
#else
    return exp2f(x);
#endif
}

// async global->LDS, 16B per lane; LDS dest = wave-uniform base + lane*16
__device__ __forceinline__ void async_cp16(const __bf16* g, __bf16* l) {
    __builtin_amdgcn_global_load_lds(
        (const __attribute__((address_space(1))) unsigned int*)g,
        (__attribute__((address_space(3))) unsigned int*)l,
        16, 0, 0);
}

#define LOG2E 1.4426950408889634f
#define C1    (0.125f * LOG2E)     // score scale folded with log2(e)
#define SMAX  12.0f                // static softmax offset (exp2 domain)

// ---------------------------------------------------------------------------
// Pre-cast: hidden fp32 -> bf16 (hbf), [qw|kw|vw|ow] fp32 -> bf16 (wbuf,
// 3072x768 row-major, K-contiguous). Memory-bound, ~90MB traffic.
// ---------------------------------------------------------------------------
__global__ __launch_bounds__(256) void precast(
    const float* __restrict__ hidden,
    const float* __restrict__ qw, const float* __restrict__ kw,
    const float* __restrict__ vw, const float* __restrict__ ow,
    __bf16* __restrict__ hbf, __bf16* __restrict__ wbuf)
{
    const int tid = threadIdx.x;
    const int bid = blockIdx.x;
    if (bid < 6144) {
        const long base = ((long)bid * 256 + tid) * 8;
        f32x4 a = *(const f32x4*)(hidden + base);
        f32x4 b = *(const f32x4*)(hidden + base + 4);
        bfx8 o;
        #pragma unroll
        for (int j = 0; j < 4; ++j) { o[j] = (__bf16)a[j]; o[4 + j] = (__bf16)b[j]; }
        *(bfx8*)(hbf + base) = o;
    } else {
        const long e = ((long)(bid - 6144) * 256 + tid) * 8;
        const int kind = (int)(e / WROWS_);
        const float* src = kind == 0 ? qw : kind == 1 ? kw : kind == 2 ? vw : ow;
        const long off = e - (long)kind * WROWS_;
        f32x4 a = *(const f32x4*)(src + off);
        f32x4 b = *(const f32x4*)(src + off + 4);
        bfx8 o;
        #pragma unroll
        for (int j = 0; j < 4; ++j) { o[j] = (__bf16)a[j]; o[4 + j] = (__bf16)b[j]; }
        *(bfx8*)(wbuf + e) = o;
    }
}

// ---------------------------------------------------------------------------
// Fused QKV GEMM, m97 recipe: 128x128 tile, BK=64, global_load_lds width=16.
// A = hbf (16384x768 bf16), B = wbuf rows [0,2304) (K-contiguous = B^T).
// LDS layout [k8][row][8]: chunk = 64 rows x one 8-col group -> DMA's
// lane*16B constraint satisfied AND ds_read_b128 frag reads walk rows
// linearly across banks (conflict-free).
// n-tile kind: blockIdx.x/6 -> 0=Q,1=K,2=V. Q,K out (B,NH,S,D); V out (B,NH,D,S).
// ---------------------------------------------------------------------------
__global__ __launch_bounds__(256) void qkv_gemm(
    const __bf16* __restrict__ hbf, const __bf16* __restrict__ wbuf,
    const float* __restrict__ qb, const float* __restrict__ kb,
    const float* __restrict__ vb,
    __bf16* __restrict__ qo, __bf16* __restrict__ ko, __bf16* __restrict__ vto)
{
    __shared__ __bf16 As[128 * 64];
    __shared__ __bf16 Bs[128 * 64];

    const int tid  = threadIdx.x;
    const int lane = tid & 63, wid = tid >> 6;
    const int quad = lane >> 4, l16 = lane & 15;
    const int n0g = blockIdx.x * 128;   // 0..2303
    const int m0  = blockIdx.y * 128;
    const int wm = (wid >> 1) * 64, wn = (wid & 1) * 64;

    f32x4 acc[4][4];
    #pragma unroll
    for (int i = 0; i < 4; ++i)
        #pragma unroll
        for (int j = 0; j < 4; ++j)
            #pragma unroll
            for (int r = 0; r < 4; ++r) acc[i][j][r] = 0.0f;

    const __bf16* Ag0 = hbf  + (long)(m0  + lane) * H_;
    const __bf16* Bg0 = wbuf + (long)(n0g + lane) * H_;

    for (int kt = 0; kt < 12; ++kt) {
        __syncthreads();
        const int k0 = kt * 64;
        #pragma unroll
        for (int c = 0; c < 4; ++c) {
            const int cc = c * 4 + wid;       // chunk 0..15
            const int k8 = cc >> 1;           // 8-col group
            const int rh = (cc & 1) * 64;     // row half
            async_cp16(Ag0 + (long)rh * H_ + k0 + k8 * 8, As + (k8 * 128 + rh) * 8);
            async_cp16(Bg0 + (long)rh * H_ + k0 + k8 * 8, Bs + (k8 * 128 + rh) * 8);
        }
        __syncthreads();
        #pragma unroll
        for (int ks = 0; ks < 2; ++ks) {
            const int k8 = ks * 4 + quad;
            bfx8 af[4], bb[4];
            #pragma unroll
            for (int t = 0; t < 4; ++t) {
                af[t] = *(const bfx8*)(As + (k8 * 128 + wm + t * 16 + l16) * 8);
                bb[t] = *(const bfx8*)(Bs + (k8 * 128 + wn + t * 16 + l16) * 8);
            }
            #pragma unroll
            for (int mt = 0; mt < 4; ++mt)
                #pragma unroll
                for (int nt = 0; nt < 4; ++nt)
                    acc[mt][nt] = MFMA(af[mt], bb[nt], acc[mt][nt]);
        }
    }

    const int kind = blockIdx.x / 6;          // 128-wide n-tiles: 6 per matrix
    const int nl0  = n0g - kind * 768;
    if (kind < 2) {
        const float* bias = (kind == 0) ? qb : kb;
        __bf16* out = (kind == 0) ? qo : ko;
        #pragma unroll
        for (int nt = 0; nt < 4; ++nt) {
            const int n = nl0 + wn + nt * 16 + l16;
            const float bv = bias[n];
            const int h = n >> 6, d = n & 63;
            #pragma unroll
            for (int mt = 0; mt < 4; ++mt) {
                #pragma unroll
                for (int r = 0; r < 4; ++r) {
                    const int m = m0 + wm + mt * 16 + quad * 4 + r;
                    const int b = m >> 10, s = m & 1023;
                    out[(((long)(b * NH_ + h) << 10) + s) * HD_ + d] =
                        (__bf16)(acc[mt][nt][r] + bv);
                }
            }
        }
    } else {
        #pragma unroll
        for (int nt = 0; nt < 4; ++nt) {
            const int n = nl0 + wn + nt * 16 + l16;
            const float bv = vb[n];
            const int h = n >> 6, d = n & 63;
            #pragma unroll
            for (int mt = 0; mt < 4; ++mt) {
                const int m = m0 + wm + mt * 16 + quad * 4;
                const int b = m >> 10, s = m & 1023;
                bfx4 pk;
                #pragma unroll
                for (int r = 0; r < 4; ++r) pk[r] = (__bf16)(acc[mt][nt][r] + bv);
                *(bfx4*)(vto + (((long)(b * NH_ + h) * HD_ + d) << 10) + s) = pk;
            }
        }
    }
}

// ---------------------------------------------------------------------------
// Attention, S^T formulation (unchanged from round 2).
// ---------------------------------------------------------------------------
__global__ __launch_bounds__(512, 4) void attn_kernel(
    const __bf16* __restrict__ q, const __bf16* __restrict__ k,
    const __bf16* __restrict__ vT, const float* __restrict__ mask,
    __bf16* __restrict__ ctx)
{
    __shared__ __bf16 Ks[64 * 72];      // [key][d]
    __shared__ __bf16 Vs[64 * 72];      // [d][key]  (V^T tile, loaded directly)
    __shared__ __bf16 Ps[8][32 * 72];   // per-wave [q][key]
    __shared__ float  Ms[1024];         // mask*log2e - SMAX

    const int tid  = threadIdx.x;
    const int lane = tid & 63, wid = tid >> 6;
    const int quad = lane >> 4, l16 = lane & 15;
    const int qc = blockIdx.x, h = blockIdx.y, b = blockIdx.z;

    const long base = ((long)(b * NH_ + h)) << 16;   // * S_ * HD_
    const __bf16* qh = q  + base;
    const __bf16* kh = k  + base;
    const __bf16* vh = vT + base;
    const float*  mb = mask + b * S_;

    Ms[tid]       = mb[tid]       * LOG2E - SMAX;
    Ms[tid + 512] = mb[tid + 512] * LOG2E - SMAX;

    const int qrow_base = qc * 256 + wid * 32;
    bfx8 qf[2][2];
    #pragma unroll
    for (int nt = 0; nt < 2; ++nt)
        #pragma unroll
        for (int ks = 0; ks < 2; ++ks)
            qf[nt][ks] = *(const bfx8*)(qh + (qrow_base + nt * 16 + l16) * HD_ +
                                        ks * 32 + quad * 8);

    f32x4 o[4][2];
    f32x4 lacc[2];
    #pragma unroll
    for (int mt = 0; mt < 4; ++mt)
        #pragma unroll
        for (int nt = 0; nt < 2; ++nt)
            #pragma unroll
            for (int r = 0; r < 4; ++r) o[mt][nt][r] = 0.0f;
    #pragma unroll
    for (int nt = 0; nt < 2; ++nt)
        #pragma unroll
        for (int r = 0; r < 4; ++r) lacc[nt][r] = 0.0f;

    const int srow = tid >> 3;
    const int scol = (tid & 7) * 8;

    for (int kt = 0; kt < 16; ++kt) {
        __syncthreads();
        *(bfx8*)(Ks + srow * 72 + scol) =
            *(const bfx8*)(kh + (kt * 64 + srow) * HD_ + scol);
        *(bfx8*)(Vs + srow * 72 + scol) =
            *(const bfx8*)(vh + srow * S_ + kt * 64 + scol);
        __syncthreads();

        #pragma unroll
        for (int t = 0; t < 4; ++t) {
            f32x4 sc[2];
            #pragma unroll
            for (int nt = 0; nt < 2; ++nt)
                #pragma unroll
                for (int r = 0; r < 4; ++r) sc[nt][r] = 0.0f;
            #pragma unroll
            for (int ks = 0; ks < 2; ++ks) {
                bfx8 kf = *(const bfx8*)(Ks + (t * 16 + l16) * 72 +
                                         ks * 32 + quad * 8);
                #pragma unroll
                for (int nt = 0; nt < 2; ++nt)
                    sc[nt] = MFMA(kf, qf[nt][ks], sc[nt]);
            }
            const f32x4 mv = *(const f32x4*)(&Ms[kt * 64 + t * 16 + quad * 4]);
            #pragma unroll
            for (int nt = 0; nt < 2; ++nt) {
                f32x4 p; bfx4 pb;
                #pragma unroll
                for (int r = 0; r < 4; ++r)
                    p[r] = fast_exp2(sc[nt][r] * C1 + mv[r]);
                lacc[nt] += p;
                #pragma unroll
                for (int r = 0; r < 4; ++r) pb[r] = (__bf16)p[r];
                *(bfx4*)(&Ps[wid][(nt * 16 + l16) * 72 + t * 16 + quad * 4]) = pb;
            }
        }

        #pragma unroll
        for (int ks = 0; ks < 2; ++ks) {
            const int koff = ks * 32 + quad * 8;
            bfx8 pf[2];
            #pragma unroll
            for (int nt = 0; nt < 2; ++nt)
                pf[nt] = *(const bfx8*)(&Ps[wid][(nt * 16 + l16) * 72 + koff]);
            #pragma unroll
            for (int mt = 0; mt < 4; ++mt) {
                bfx8 vf = *(const bfx8*)(Vs + (mt * 16 + l16) * 72 + koff);
                #pragma unroll
                for (int nt = 0; nt < 2; ++nt)
                    o[mt][nt] = MFMA(vf, pf[nt], o[mt][nt]);
            }
        }
    }

    float linv[2];
    #pragma unroll
    for (int nt = 0; nt < 2; ++nt) {
        float s = lacc[nt][0] + lacc[nt][1] + lacc[nt][2] + lacc[nt][3];
        s += __shfl_xor(s, 16);
        s += __shfl_xor(s, 32);
        linv[nt] = 1.0f / s;
    }

    #pragma unroll
    for (int nt = 0; nt < 2; ++nt) {
        #pragma unroll
        for (int mt = 0; mt < 4; ++mt) {
            bfx4 ov;
            #pragma unroll
            for (int r = 0; r < 4; ++r)
                ov[r] = (__bf16)(o[mt][nt][r] * linv[nt]);
            const int qrow = qrow_base + nt * 16 + l16;
            *(bfx4*)(ctx + ((long)(b << 10) + qrow) * H_ + h * HD_ +
                     mt * 16 + quad * 4) = ov;
        }
    }
}

// ---------------------------------------------------------------------------
// Output projection + residual, m97 recipe. B = wbuf rows [2304,3072).
// ---------------------------------------------------------------------------
__global__ __launch_bounds__(256) void out_gemm(
    const __bf16* __restrict__ ctx, const __bf16* __restrict__ wbuf,
    const float* __restrict__ ob, const float* __restrict__ hidden,
    float* __restrict__ xres)
{
    __shared__ __bf16 As[128 * 64];
    __shared__ __bf16 Bs[128 * 64];

    const int tid  = threadIdx.x;
    const int lane = tid & 63, wid = tid >> 6;
    const int quad = lane >> 4, l16 = lane & 15;
    const int n0 = blockIdx.x * 128;
    const int m0 = blockIdx.y * 128;
    const int wm = (wid >> 1) * 64, wn = (wid & 1) * 64;

    f32x4 acc[4][4];
    #pragma unroll
    for (int i = 0; i < 4; ++i)
        #pragma unroll
        for (int j = 0; j < 4; ++j)
            #pragma unroll
            for (int r = 0; r < 4; ++r) acc[i][j][r] = 0.0f;

    const __bf16* Ag0 = ctx  + (long)(m0 + lane) * H_;
    const __bf16* Bg0 = wbuf + (long)(3 * 768 + n0 + lane) * H_;

    for (int kt = 0; kt < 12; ++kt) {
        __syncthreads();
        const int k0 = kt * 64;
        #pragma unroll
        for (int c = 0; c < 4; ++c) {
            const int cc = c * 4 + wid;
            const int k8 = cc >> 1;
            const int rh = (cc & 1) * 64;
            async_cp16(Ag0 + (long)rh * H_ + k0 + k8 * 8, As + (k8 * 128 + rh) * 8);
            async_cp16(Bg0 + (long)rh * H_ + k0 + k8 * 8, Bs + (k8 * 128 + rh) * 8);
        }
        __syncthreads();
        #pragma unroll
        for (int ks = 0; ks < 2; ++ks) {
            const int k8 = ks * 4 + quad;
            bfx8 af[4], bb[4];
            #pragma unroll
            for (int t = 0; t < 4; ++t) {
                af[t] = *(const bfx8*)(As + (k8 * 128 + wm + t * 16 + l16) * 8);
                bb[t] = *(const bfx8*)(Bs + (k8 * 128 + wn + t * 16 + l16) * 8);
            }
            #pragma unroll
            for (int mt = 0; mt < 4; ++mt)
                #pragma unroll
                for (int nt = 0; nt < 4; ++nt)
                    acc[mt][nt] = MFMA(af[mt], bb[nt], acc[mt][nt]);
        }
    }

    #pragma unroll
    for (int nt = 0; nt < 4; ++nt) {
        const int n = n0 + wn + nt * 16 + l16;
        const float bv = ob[n];
        #pragma unroll
        for (int mt = 0; mt < 4; ++mt) {
            #pragma unroll
            for (int r = 0; r < 4; ++r) {
                const int m = m0 + wm + mt * 16 + quad * 4 + r;
                const long idx = (long)m * H_ + n;
                xres[idx] = acc[mt][nt][r] + bv + hidden[idx];
            }
        }
    }
}

// ---------------------------------------------------------------------------
// LayerNorm over H=768, wave per row
// ---------------------------------------------------------------------------
__global__ __launch_bounds__(256) void ln_kernel(
    const float* __restrict__ xres, const float* __restrict__ gamma,
    const float* __restrict__ beta, float* __restrict__ out)
{
    const int tid = threadIdx.x, lane = tid & 63, wid = tid >> 6;
    const long row = (long)blockIdx.x * 4 + wid;
    const float* xr = xres + row * H_;

    f32x4 xv[3];
    float sum = 0.0f, sumsq = 0.0f;
    #pragma unroll
    for (int c = 0; c < 3; ++c) {
        xv[c] = *(const f32x4*)(xr + c * 256 + lane * 4);
        #pragma unroll
        for (int j = 0; j < 4; ++j) { sum += xv[c][j]; sumsq += xv[c][j] * xv[c][j]; }
    }
    #pragma unroll
    for (int off = 1; off < 64; off <<= 1) {
        sum   += __shfl_xor(sum, off);
        sumsq += __shfl_xor(sumsq, off);
    }
    const float mean = sum * (1.0f / 768.0f);
    const float var  = sumsq * (1.0f / 768.0f) - mean * mean;
    const float rstd = rsqrtf(var + 1e-12f);

    float* orow = out + row * H_;
    #pragma unroll
    for (int c = 0; c < 3; ++c) {
        f32x4 g  = *(const f32x4*)(gamma + c * 256 + lane * 4);
        f32x4 bt = *(const f32x4*)(beta  + c * 256 + lane * 4);
        f32x4 ov;
        #pragma unroll
        for (int j = 0; j < 4; ++j) ov[j] = (xv[c][j] - mean) * rstd * g[j] + bt[j];
        *(f32x4*)(orow + c * 256 + lane * 4) = ov;
    }
}

extern "C" void kernel_launch(void* const* d_in, const int* in_sizes, int n_in,
                              void* d_out, int out_size, void* d_ws, size_t ws_size,
                              hipStream_t stream)
{
    const float* hidden = (const float*)d_in[0];
    const float* mask   = (const float*)d_in[1];
    const float* qw = (const float*)d_in[2];
    const float* qb = (const float*)d_in[3];
    const float* kw = (const float*)d_in[4];
    const float* kb = (const float*)d_in[5];
    const float* vw = (const float*)d_in[6];
    const float* vb = (const float*)d_in[7];
    const float* ow = (const float*)d_in[8];
    const float* ob = (const float*)d_in[9];
    const float* gamma = (const float*)d_in[10];
    const float* beta  = (const float*)d_in[11];
    float* out = (float*)d_out;

    // ws layout (96 MB total, proven safe):
    //   [0,24)  hbf  (hidden bf16)  -> ctx aliases after qkv_gemm
    //   [24,48) q    (B,NH,S,D)
    //   [48,72) k    (B,NH,S,D)
    //   [72,96) vt   (B,NH,D,S)
    //   xres fp32 aliases [24,72) (q,k dead after attn)
    // wbuf (bf16 weights, 4.7 MB) lives in d_out until ln overwrites it.
    char* ws = (char*)d_ws;
    const size_t SZB = (size_t)BS_ * H_ * 2;     // 25,165,824 B per bf16 buffer
    __bf16* hbf  = (__bf16*)ws;
    __bf16* qws  = (__bf16*)(ws + SZB);
    __bf16* kws  = (__bf16*)(ws + 2 * SZB);
    __bf16* vtws = (__bf16*)(ws + 3 * SZB);
    __bf16* cws  = hbf;                          // ctx aliases hbf
    float*  xres = (float*)(ws + SZB);           // aliases q,k
    __bf16* wbuf = (__bf16*)d_out;               // scratch inside output buffer

    precast<<<dim3(7296), 256, 0, stream>>>(hidden, qw, kw, vw, ow, hbf, wbuf);
    qkv_gemm<<<dim3(18, 128), 256, 0, stream>>>(hbf, wbuf, qb, kb, vb,
                                                qws, kws, vtws);
    attn_kernel<<<dim3(4, 12, 16), 512, 0, stream>>>(qws, kws, vtws, mask, cws);
    out_gemm<<<dim3(6, 128), 256, 0, stream>>>(cws, wbuf, ob, hidden, xres);
    ln_kernel<<<dim3(4096), 256, 0, stream>>>(xres, gamma, beta, out);
}

// Round 4
// 333.624 us; speedup vs baseline: 1.7064x; 1.2549x over previous
//
#include <hip/hip_runtime.h>
#include <hip/hip_bf16.h>

#define B_  16
#define S_  1024
#define H_  768
#define NH_ 12
#define HD_ 64
#define BS_ (B_*S_)   // 16384
#define WROWS_ 589824 // 768*768 per weight matrix

typedef __bf16 bfx8 __attribute__((ext_vector_type(8)));
typedef __bf16 bfx4 __attribute__((ext_vector_type(4)));
typedef float  f32x4 __attribute__((ext_vector_type(4)));

#define MFMA(a,b,c) __builtin_amdgcn_mfma_f32_16x16x32_bf16(a,b,c,0,0,0)

__device__ __forceinline__ float fast_exp2(float x) {
#if __has_builtin(__builtin_amdgcn_exp2f)
    return __builtin_amdgcn_exp2f(x);
#else
    return exp2f(x);
#endif
}

// async global->LDS, 16B per lane; LDS dest = wave-uniform base + lane*16
__device__ __forceinline__ void async_cp16(const __bf16* g, __bf16* l) {
    __builtin_amdgcn_global_load_lds(
        (const __attribute__((address_space(1))) unsigned int*)g,
        (__attribute__((address_space(3))) unsigned int*)l,
        16, 0, 0);
}

#define LOG2E 1.4426950408889634f
#define C1    (0.125f * LOG2E)     // score scale folded with log2(e)
#define SMAX  12.0f                // static softmax offset (exp2 domain)

// ---------------------------------------------------------------------------
// Pre-cast: hidden fp32 -> bf16 (hbf), [qw|kw|vw|ow] fp32 -> bf16 (wbuf).
// ---------------------------------------------------------------------------
__global__ __launch_bounds__(256) void precast(
    const float* __restrict__ hidden,
    const float* __restrict__ qw, const float* __restrict__ kw,
    const float* __restrict__ vw, const float* __restrict__ ow,
    __bf16* __restrict__ hbf, __bf16* __restrict__ wbuf)
{
    const int tid = threadIdx.x;
    const int bid = blockIdx.x;
    if (bid < 6144) {
        const long base = ((long)bid * 256 + tid) * 8;
        f32x4 a = *(const f32x4*)(hidden + base);
        f32x4 b = *(const f32x4*)(hidden + base + 4);
        bfx8 o;
        #pragma unroll
        for (int j = 0; j < 4; ++j) { o[j] = (__bf16)a[j]; o[4 + j] = (__bf16)b[j]; }
        *(bfx8*)(hbf + base) = o;
    } else {
        const long e = ((long)(bid - 6144) * 256 + tid) * 8;
        const int kind = (int)(e / WROWS_);
        const float* src = kind == 0 ? qw : kind == 1 ? kw : kind == 2 ? vw : ow;
        const long off = e - (long)kind * WROWS_;
        f32x4 a = *(const f32x4*)(src + off);
        f32x4 b = *(const f32x4*)(src + off + 4);
        bfx8 o;
        #pragma unroll
        for (int j = 0; j < 4; ++j) { o[j] = (__bf16)a[j]; o[4 + j] = (__bf16)b[j]; }
        *(bfx8*)(wbuf + e) = o;
    }
}

// ---------------------------------------------------------------------------
// Fused QKV GEMM. 128x128 tile, BK=64, global_load_lds width=16.
// LDS: unpadded [row][64] with XOR swizzle: logical col-group c8 (8 bf16)
// stored at physical c8 ^ (row&7). DMA chunk = 8 rows x 128B: lane reads
// global c8_log = (lane&7)^(lane>>3&7) -> contiguous aligned 128-B segments
// (coalesced); frag ds_read_b128 lands 2-way per bank group (free).
// ---------------------------------------------------------------------------
__global__ __launch_bounds__(256) void qkv_gemm(
    const __bf16* __restrict__ hbf, const __bf16* __restrict__ wbuf,
    const float* __restrict__ qb, const float* __restrict__ kb,
    const float* __restrict__ vb,
    __bf16* __restrict__ qo, __bf16* __restrict__ ko, __bf16* __restrict__ vto)
{
    __shared__ __bf16 As[128 * 64];
    __shared__ __bf16 Bs[128 * 64];

    const int tid  = threadIdx.x;
    const int lane = tid & 63, wid = tid >> 6;
    const int quad = lane >> 4, l16 = lane & 15;
    const int n0g = blockIdx.x * 128;   // 0..2303
    const int m0  = blockIdx.y * 128;
    const int wm = (wid >> 1) * 64, wn = (wid & 1) * 64;

    f32x4 acc[4][4];
    #pragma unroll
    for (int i = 0; i < 4; ++i)
        #pragma unroll
        for (int j = 0; j < 4; ++j)
            #pragma unroll
            for (int r = 0; r < 4; ++r) acc[i][j][r] = 0.0f;

    // DMA addressing: row-in-chunk = lane>>3, swizzled col group
    const int drow = lane >> 3;
    const int dcol = ((lane & 7) ^ (drow & 7)) * 8;
    const __bf16* Ag0 = hbf  + (long)(m0  + drow) * H_ + dcol;
    const __bf16* Bg0 = wbuf + (long)(n0g + drow) * H_ + dcol;
    const int swz = (l16 & 7);          // reader swizzle term

    for (int kt = 0; kt < 12; ++kt) {
        __syncthreads();
        const int k0 = kt * 64;
        #pragma unroll
        for (int c = 0; c < 4; ++c) {
            const int cc = c * 4 + wid;       // chunk 0..15 (8 rows each)
            async_cp16(Ag0 + (long)cc * 8 * H_ + k0, As + cc * 512);
            async_cp16(Bg0 + (long)cc * 8 * H_ + k0, Bs + cc * 512);
        }
        __syncthreads();
        #pragma unroll
        for (int ks = 0; ks < 2; ++ks) {
            const int cg = (ks * 4 + quad);
            const int coff = (cg ^ swz) * 8;
            bfx8 af[4], bb[4];
            #pragma unroll
            for (int t = 0; t < 4; ++t) {
                af[t] = *(const bfx8*)(As + (wm + t * 16 + l16) * 64 + coff);
                bb[t] = *(const bfx8*)(Bs + (wn + t * 16 + l16) * 64 + coff);
            }
            #pragma unroll
            for (int mt = 0; mt < 4; ++mt)
                #pragma unroll
                for (int nt = 0; nt < 4; ++nt)
                    acc[mt][nt] = MFMA(af[mt], bb[nt], acc[mt][nt]);
        }
    }

    const int kind = blockIdx.x / 6;          // 128-wide n-tiles: 6 per matrix
    const int nl0  = n0g - kind * 768;
    if (kind < 2) {
        const float* bias = (kind == 0) ? qb : kb;
        __bf16* out = (kind == 0) ? qo : ko;
        #pragma unroll
        for (int nt = 0; nt < 4; ++nt) {
            const int n = nl0 + wn + nt * 16 + l16;
            const float bv = bias[n];
            const int h = n >> 6, d = n & 63;
            #pragma unroll
            for (int mt = 0; mt < 4; ++mt) {
                #pragma unroll
                for (int r = 0; r < 4; ++r) {
                    const int m = m0 + wm + mt * 16 + quad * 4 + r;
                    const int b = m >> 10, s = m & 1023;
                    out[(((long)(b * NH_ + h) << 10) + s) * HD_ + d] =
                        (__bf16)(acc[mt][nt][r] + bv);
                }
            }
        }
    } else {
        #pragma unroll
        for (int nt = 0; nt < 4; ++nt) {
            const int n = nl0 + wn + nt * 16 + l16;
            const float bv = vb[n];
            const int h = n >> 6, d = n & 63;
            #pragma unroll
            for (int mt = 0; mt < 4; ++mt) {
                const int m = m0 + wm + mt * 16 + quad * 4;
                const int b = m >> 10, s = m & 1023;
                bfx4 pk;
                #pragma unroll
                for (int r = 0; r < 4; ++r) pk[r] = (__bf16)(acc[mt][nt][r] + bv);
                *(bfx4*)(vto + (((long)(b * NH_ + h) * HD_ + d) << 10) + s) = pk;
            }
        }
    }
}

// ---------------------------------------------------------------------------
// Attention, S^T formulation. 8 waves x 32 q-rows. 128-key rounds (half the
// barriers of r2) with K and V^T staged via swizzled async DMA.
//   Ks[128][64]  (key-major, global rows contiguous 128B)
//   Vs[64][128]  (d-major, global rows 256B @ stride 2KB)
// Softmax: static-max exp2 domain; P via per-wave LDS (layout from r2).
// ---------------------------------------------------------------------------
__global__ __launch_bounds__(512, 4) void attn_kernel(
    const __bf16* __restrict__ q, const __bf16* __restrict__ k,
    const __bf16* __restrict__ vT, const float* __restrict__ mask,
    __bf16* __restrict__ ctx)
{
    __shared__ __bf16 Ks[128 * 64];     // 16 KB
    __shared__ __bf16 Vs[64 * 128];     // 16 KB
    __shared__ __bf16 Ps[8][32 * 72];   // 36 KB per-wave [q][key(64)]
    __shared__ float  Ms[1024];         // 4 KB  mask*log2e - SMAX

    const int tid  = threadIdx.x;
    const int lane = tid & 63, wid = tid >> 6;
    const int quad = lane >> 4, l16 = lane & 15;
    const int qc = blockIdx.x, h = blockIdx.y, b = blockIdx.z;

    const long base = ((long)(b * NH_ + h)) << 16;   // * S_ * HD_
    const __bf16* qh = q  + base;
    const __bf16* kh = k  + base;
    const __bf16* vh = vT + base;
    const float*  mb = mask + b * S_;

    Ms[tid]       = mb[tid]       * LOG2E - SMAX;
    Ms[tid + 512] = mb[tid + 512] * LOG2E - SMAX;

    const int qrow_base = qc * 256 + wid * 32;
    bfx8 qf[2][2];
    #pragma unroll
    for (int nt = 0; nt < 2; ++nt)
        #pragma unroll
        for (int ks = 0; ks < 2; ++ks)
            qf[nt][ks] = *(const bfx8*)(qh + (qrow_base + nt * 16 + l16) * HD_ +
                                        ks * 32 + quad * 8);

    f32x4 o[4][2];
    f32x4 lacc[2];
    #pragma unroll
    for (int mt = 0; mt < 4; ++mt)
        #pragma unroll
        for (int nt = 0; nt < 2; ++nt)
            #pragma unroll
            for (int r = 0; r < 4; ++r) o[mt][nt][r] = 0.0f;
    #pragma unroll
    for (int nt = 0; nt < 2; ++nt)
        #pragma unroll
        for (int r = 0; r < 4; ++r) lacc[nt][r] = 0.0f;

    // DMA addressing
    const int krow = lane >> 3;                        // K: 8 keys/chunk
    const int kcol = ((lane & 7) ^ (krow & 7)) * 8;
    const int vrow = lane >> 4;                        // V: 4 d-rows/chunk
    const int swz  = (l16 & 7);

    for (int kt = 0; kt < 8; ++kt) {
        __syncthreads();
        #pragma unroll
        for (int c = 0; c < 2; ++c) {
            const int cc = wid * 2 + c;     // chunk 0..15
            async_cp16(kh + (long)(kt * 128 + cc * 8 + krow) * HD_ + kcol,
                       Ks + cc * 512);
            const int vcol = ((lane & 15) ^ ((c << 2) | vrow)) * 8;
            async_cp16(vh + (long)(cc * 4 + vrow) * S_ + kt * 128 + vcol,
                       Vs + cc * 512);
        }
        __syncthreads();

        #pragma unroll
        for (int kh2 = 0; kh2 < 2; ++kh2) {
            // S^T = K * Q^T over 64 keys
            #pragma unroll
            for (int t = 0; t < 4; ++t) {
                f32x4 sc[2];
                #pragma unroll
                for (int nt = 0; nt < 2; ++nt)
                    #pragma unroll
                    for (int r = 0; r < 4; ++r) sc[nt][r] = 0.0f;
                #pragma unroll
                for (int ks = 0; ks < 2; ++ks) {
                    bfx8 kf = *(const bfx8*)(Ks + (kh2 * 64 + t * 16 + l16) * 64 +
                                             ((ks * 4 + quad) ^ swz) * 8);
                    #pragma unroll
                    for (int nt = 0; nt < 2; ++nt)
                        sc[nt] = MFMA(kf, qf[nt][ks], sc[nt]);
                }
                const f32x4 mv = *(const f32x4*)(&Ms[kt * 128 + kh2 * 64 +
                                                    t * 16 + quad * 4]);
                #pragma unroll
                for (int nt = 0; nt < 2; ++nt) {
                    f32x4 p; bfx4 pb;
                    #pragma unroll
                    for (int r = 0; r < 4; ++r)
                        p[r] = fast_exp2(sc[nt][r] * C1 + mv[r]);
                    lacc[nt] += p;
                    #pragma unroll
                    for (int r = 0; r < 4; ++r) pb[r] = (__bf16)p[r];
                    *(bfx4*)(&Ps[wid][(nt * 16 + l16) * 72 + t * 16 + quad * 4]) = pb;
                }
            }
            // O^T += V^T * P^T ; per-wave Ps, same-wave ordering -> no barrier
            #pragma unroll
            for (int ks = 0; ks < 2; ++ks) {
                const int koff = ks * 32 + quad * 8;
                bfx8 pf[2];
                #pragma unroll
                for (int nt = 0; nt < 2; ++nt)
                    pf[nt] = *(const bfx8*)(&Ps[wid][(nt * 16 + l16) * 72 + koff]);
                const int vcg = (kh2 * 8 + ks * 4 + quad) ^ swz;
                #pragma unroll
                for (int mt = 0; mt < 4; ++mt) {
                    bfx8 vf = *(const bfx8*)(Vs + (mt * 16 + l16) * 128 + vcg * 8);
                    #pragma unroll
                    for (int nt = 0; nt < 2; ++nt)
                        o[mt][nt] = MFMA(vf, pf[nt], o[mt][nt]);
                }
            }
        }
    }

    float linv[2];
    #pragma unroll
    for (int nt = 0; nt < 2; ++nt) {
        float s = lacc[nt][0] + lacc[nt][1] + lacc[nt][2] + lacc[nt][3];
        s += __shfl_xor(s, 16);
        s += __shfl_xor(s, 32);
        linv[nt] = 1.0f / s;
    }

    #pragma unroll
    for (int nt = 0; nt < 2; ++nt) {
        #pragma unroll
        for (int mt = 0; mt < 4; ++mt) {
            bfx4 ov;
            #pragma unroll
            for (int r = 0; r < 4; ++r)
                ov[r] = (__bf16)(o[mt][nt][r] * linv[nt]);
            const int qrow = qrow_base + nt * 16 + l16;
            *(bfx4*)(ctx + ((long)(b << 10) + qrow) * H_ + h * HD_ +
                     mt * 16 + quad * 4) = ov;
        }
    }
}

// ---------------------------------------------------------------------------
// Output projection + residual, swizzled-DMA staging. B = wbuf rows [2304,3072).
// ---------------------------------------------------------------------------
__global__ __launch_bounds__(256) void out_gemm(
    const __bf16* __restrict__ ctx, const __bf16* __restrict__ wbuf,
    const float* __restrict__ ob, const float* __restrict__ hidden,
    float* __restrict__ xres)
{
    __shared__ __bf16 As[128 * 64];
    __shared__ __bf16 Bs[128 * 64];

    const int tid  = threadIdx.x;
    const int lane = tid & 63, wid = tid >> 6;
    const int quad = lane >> 4, l16 = lane & 15;
    const int n0 = blockIdx.x * 128;
    const int m0 = blockIdx.y * 128;
    const int wm = (wid >> 1) * 64, wn = (wid & 1) * 64;

    f32x4 acc[4][4];
    #pragma unroll
    for (int i = 0; i < 4; ++i)
        #pragma unroll
        for (int j = 0; j < 4; ++j)
            #pragma unroll
            for (int r = 0; r < 4; ++r) acc[i][j][r] = 0.0f;

    const int drow = lane >> 3;
    const int dcol = ((lane & 7) ^ (drow & 7)) * 8;
    const __bf16* Ag0 = ctx  + (long)(m0 + drow) * H_ + dcol;
    const __bf16* Bg0 = wbuf + (long)(3 * 768 + n0 + drow) * H_ + dcol;
    const int swz = (l16 & 7);

    for (int kt = 0; kt < 12; ++kt) {
        __syncthreads();
        const int k0 = kt * 64;
        #pragma unroll
        for (int c = 0; c < 4; ++c) {
            const int cc = c * 4 + wid;
            async_cp16(Ag0 + (long)cc * 8 * H_ + k0, As + cc * 512);
            async_cp16(Bg0 + (long)cc * 8 * H_ + k0, Bs + cc * 512);
        }
        __syncthreads();
        #pragma unroll
        for (int ks = 0; ks < 2; ++ks) {
            const int coff = ((ks * 4 + quad) ^ swz) * 8;
            bfx8 af[4], bb[4];
            #pragma unroll
            for (int t = 0; t < 4; ++t) {
                af[t] = *(const bfx8*)(As + (wm + t * 16 + l16) * 64 + coff);
                bb[t] = *(const bfx8*)(Bs + (wn + t * 16 + l16) * 64 + coff);
            }
            #pragma unroll
            for (int mt = 0; mt < 4; ++mt)
                #pragma unroll
                for (int nt = 0; nt < 4; ++nt)
                    acc[mt][nt] = MFMA(af[mt], bb[nt], acc[mt][nt]);
        }
    }

    #pragma unroll
    for (int nt = 0; nt < 4; ++nt) {
        const int n = n0 + wn + nt * 16 + l16;
        const float bv = ob[n];
        #pragma unroll
        for (int mt = 0; mt < 4; ++mt) {
            #pragma unroll
            for (int r = 0; r < 4; ++r) {
                const int m = m0 + wm + mt * 16 + quad * 4 + r;
                const long idx = (long)m * H_ + n;
                xres[idx] = acc[mt][nt][r] + bv + hidden[idx];
            }
        }
    }
}

// ---------------------------------------------------------------------------
// LayerNorm over H=768, wave per row
// ---------------------------------------------------------------------------
__global__ __launch_bounds__(256) void ln_kernel(
    const float* __restrict__ xres, const float* __restrict__ gamma,
    const float* __restrict__ beta, float* __restrict__ out)
{
    const int tid = threadIdx.x, lane = tid & 63, wid = tid >> 6;
    const long row = (long)blockIdx.x * 4 + wid;
    const float* xr = xres + row * H_;

    f32x4 xv[3];
    float sum = 0.0f, sumsq = 0.0f;
    #pragma unroll
    for (int c = 0; c < 3; ++c) {
        xv[c] = *(const f32x4*)(xr + c * 256 + lane * 4);
        #pragma unroll
        for (int j = 0; j < 4; ++j) { sum += xv[c][j]; sumsq += xv[c][j] * xv[c][j]; }
    }
    #pragma unroll
    for (int off = 1; off < 64; off <<= 1) {
        sum   += __shfl_xor(sum, off);
        sumsq += __shfl_xor(sumsq, off);
    }
    const float mean = sum * (1.0f / 768.0f);
    const float var  = sumsq * (1.0f / 768.0f) - mean * mean;
    const float rstd = rsqrtf(var + 1e-12f);

    float* orow = out + row * H_;
    #pragma unroll
    for (int c = 0; c < 3; ++c) {
        f32x4 g  = *(const f32x4*)(gamma + c * 256 + lane * 4);
        f32x4 bt = *(const f32x4*)(beta  + c * 256 + lane * 4);
        f32x4 ov;
        #pragma unroll
        for (int j = 0; j < 4; ++j) ov[j] = (xv[c][j] - mean) * rstd * g[j] + bt[j];
        *(f32x4*)(orow + c * 256 + lane * 4) = ov;
    }
}

extern "C" void kernel_launch(void* const* d_in, const int* in_sizes, int n_in,
                              void* d_out, int out_size, void* d_ws, size_t ws_size,
                              hipStream_t stream)
{
    const float* hidden = (const float*)d_in[0];
    const float* mask   = (const float*)d_in[1];
    const float* qw = (const float*)d_in[2];
    const float* qb = (const float*)d_in[3];
    const float* kw = (const float*)d_in[4];
    const float* kb = (const float*)d_in[5];
    const float* vw = (const float*)d_in[6];
    const float* vb = (const float*)d_in[7];
    const float* ow = (const float*)d_in[8];
    const float* ob = (const float*)d_in[9];
    const float* gamma = (const float*)d_in[10];
    const float* beta  = (const float*)d_in[11];
    float* out = (float*)d_out;

    // ws layout (96 MB): [0,24) hbf->ctx alias; [24,48) q; [48,72) k; [72,96) vt
    // xres fp32 aliases [24,72). wbuf bf16 weights live in d_out until ln.
    char* ws = (char*)d_ws;
    const size_t SZB = (size_t)BS_ * H_ * 2;     // 25,165,824 B per bf16 buffer
    __bf16* hbf  = (__bf16*)ws;
    __bf16* qws  = (__bf16*)(ws + SZB);
    __bf16* kws  = (__bf16*)(ws + 2 * SZB);
    __bf16* vtws = (__bf16*)(ws + 3 * SZB);
    __bf16* cws  = hbf;                          // ctx aliases hbf
    float*  xres = (float*)(ws + SZB);           // aliases q,k
    __bf16* wbuf = (__bf16*)d_out;               // scratch inside output buffer

    precast<<<dim3(7296), 256, 0, stream>>>(hidden, qw, kw, vw, ow, hbf, wbuf);
    qkv_gemm<<<dim3(18, 128), 256, 0, stream>>>(hbf, wbuf, qb, kb, vb,
                                                qws, kws, vtws);
    attn_kernel<<<dim3(4, 12, 16), 512, 0, stream>>>(qws, kws, vtws, mask, cws);
    out_gemm<<<dim3(6, 128), 256, 0, stream>>>(cws, wbuf, ob, hidden, xres);
    ln_kernel<<<dim3(4096), 256, 0, stream>>>(xres, gamma, beta, out);
}

// Round 5
// 325.556 us; speedup vs baseline: 1.7487x; 1.0248x over previous
//
#include <hip/hip_runtime.h>
#include <hip/hip_bf16.h>

#define B_  16
#define S_  1024
#define H_  768
#define NH_ 12
#define HD_ 64
#define BS_ (B_*S_)   // 16384
#define WROWS_ 589824 // 768*768 per weight matrix

typedef __bf16 bfx8 __attribute__((ext_vector_type(8)));
typedef __bf16 bfx4 __attribute__((ext_vector_type(4)));
typedef float  f32x4 __attribute__((ext_vector_type(4)));

#define MFMA(a,b,c) __builtin_amdgcn_mfma_f32_16x16x32_bf16(a,b,c,0,0,0)

__device__ __forceinline__ float fast_exp2(float x) {
#if __has_builtin(__builtin_amdgcn_exp2f)
    return __builtin_amdgcn_exp2f(x);
#else
    return exp2f(x);
#endif
}

// async global->LDS, 16B per lane; LDS dest = wave-uniform base + lane*16
__device__ __forceinline__ void async_cp16(const __bf16* g, __bf16* l) {
    __builtin_amdgcn_global_load_lds(
        (const __attribute__((address_space(1))) unsigned int*)g,
        (__attribute__((address_space(3))) unsigned int*)l,
        16, 0, 0);
}

#define LOG2E 1.4426950408889634f
#define C1    (0.125f * LOG2E)     // score scale folded with log2(e)
#define SMAX  12.0f                // static softmax offset (exp2 domain)

// ---------------------------------------------------------------------------
// Pre-cast: hidden fp32 -> bf16 (hbf), [qw|kw|vw|ow] fp32 -> bf16 (wbuf).
// ---------------------------------------------------------------------------
__global__ __launch_bounds__(256) void precast(
    const float* __restrict__ hidden,
    const float* __restrict__ qw, const float* __restrict__ kw,
    const float* __restrict__ vw, const float* __restrict__ ow,
    __bf16* __restrict__ hbf, __bf16* __restrict__ wbuf)
{
    const int tid = threadIdx.x;
    const int bid = blockIdx.x;
    if (bid < 6144) {
        const long base = ((long)bid * 256 + tid) * 8;
        f32x4 a = *(const f32x4*)(hidden + base);
        f32x4 b = *(const f32x4*)(hidden + base + 4);
        bfx8 o;
        #pragma unroll
        for (int j = 0; j < 4; ++j) { o[j] = (__bf16)a[j]; o[4 + j] = (__bf16)b[j]; }
        *(bfx8*)(hbf + base) = o;
    } else {
        const long e = ((long)(bid - 6144) * 256 + tid) * 8;
        const int kind = (int)(e / WROWS_);
        const float* src = kind == 0 ? qw : kind == 1 ? kw : kind == 2 ? vw : ow;
        const long off = e - (long)kind * WROWS_;
        f32x4 a = *(const f32x4*)(src + off);
        f32x4 b = *(const f32x4*)(src + off + 4);
        bfx8 o;
        #pragma unroll
        for (int j = 0; j < 4; ++j) { o[j] = (__bf16)a[j]; o[4 + j] = (__bf16)b[j]; }
        *(bfx8*)(wbuf + e) = o;
    }
}

// ---------------------------------------------------------------------------
// Fused QKV GEMM. 128x128 tile, BK=64, swizzled global_load_lds staging.
// XCD-chunked block map: xcd = bid&7 gets y-range [16*xcd,16*xcd+16) so the
// A-panels one XCD touches (3.1 MB) stay resident in its private L2.
// Q/K blocks swap MFMA operands (A=weight) so acc r-regs span d: epilogue
// packs bfx4 -> per-wave LDS tile (aliases As/Bs after barrier) -> bfx8
// reads -> 8 fully-linear 1KB/instr global stores. V keeps normal order
// (r spans s = V^T inner dim) with the same transpose trick.
// ---------------------------------------------------------------------------
__global__ __launch_bounds__(256) void qkv_gemm(
    const __bf16* __restrict__ hbf, const __bf16* __restrict__ wbuf,
    const float* __restrict__ qb, const float* __restrict__ kb,
    const float* __restrict__ vb,
    __bf16* __restrict__ qo, __bf16* __restrict__ ko, __bf16* __restrict__ vto)
{
    __shared__ __bf16 smem[18432];      // 36864 B: As|Bs in [0,16384), Ts all
    __bf16* As = smem;                  // 8192 elems
    __bf16* Bs = smem + 8192;           // 8192 elems
    __bf16* Ts = smem;                  // epilogue: 4 waves x 4608 elems

    const int bid  = blockIdx.x;
    const int xcd  = bid & 7;
    const int slot = bid >> 3;          // 0..287
    const int xx   = slot >> 4;         // 0..17  (n-tile / weight panel)
    const int yy   = xcd * 16 + (slot & 15);   // 0..127 (m-tile)

    const int tid  = threadIdx.x;
    const int lane = tid & 63, wid = tid >> 6;
    const int quad = lane >> 4, l16 = lane & 15;
    const int n0g = xx * 128;
    const int m0  = yy * 128;
    const int wm = (wid >> 1) * 64, wn = (wid & 1) * 64;
    const int kind = xx / 6;            // 0=Q,1=K,2=V
    const int nl0  = n0g - kind * 768;

    f32x4 acc[4][4];
    #pragma unroll
    for (int i = 0; i < 4; ++i)
        #pragma unroll
        for (int j = 0; j < 4; ++j)
            #pragma unroll
            for (int r = 0; r < 4; ++r) acc[i][j][r] = 0.0f;

    const int drow = lane >> 3;
    const int dcol = ((lane & 7) ^ (drow & 7)) * 8;
    const __bf16* Ag0 = hbf  + (long)(m0  + drow) * H_ + dcol;
    const __bf16* Bg0 = wbuf + (long)(n0g + drow) * H_ + dcol;
    const int swz = (l16 & 7);

    for (int kt = 0; kt < 12; ++kt) {
        __syncthreads();
        const int k0 = kt * 64;
        #pragma unroll
        for (int c = 0; c < 4; ++c) {
            const int cc = c * 4 + wid;
            async_cp16(Ag0 + (long)cc * 8 * H_ + k0, As + cc * 512);
            async_cp16(Bg0 + (long)cc * 8 * H_ + k0, Bs + cc * 512);
        }
        __syncthreads();
        if (kind < 2) {
            #pragma unroll
            for (int ks = 0; ks < 2; ++ks) {
                const int coff = ((ks * 4 + quad) ^ swz) * 8;
                bfx8 af[4], bb[4];
                #pragma unroll
                for (int t = 0; t < 4; ++t) {
                    af[t] = *(const bfx8*)(As + (wm + t * 16 + l16) * 64 + coff);
                    bb[t] = *(const bfx8*)(Bs + (wn + t * 16 + l16) * 64 + coff);
                }
                #pragma unroll
                for (int mt = 0; mt < 4; ++mt)   // mt = weight tile (rows=d)
                    #pragma unroll
                    for (int nt = 0; nt < 4; ++nt)  // nt = hidden tile (cols=s)
                        acc[mt][nt] = MFMA(bb[mt], af[nt], acc[mt][nt]);
            }
        } else {
            #pragma unroll
            for (int ks = 0; ks < 2; ++ks) {
                const int coff = ((ks * 4 + quad) ^ swz) * 8;
                bfx8 af[4], bb[4];
                #pragma unroll
                for (int t = 0; t < 4; ++t) {
                    af[t] = *(const bfx8*)(As + (wm + t * 16 + l16) * 64 + coff);
                    bb[t] = *(const bfx8*)(Bs + (wn + t * 16 + l16) * 64 + coff);
                }
                #pragma unroll
                for (int mt = 0; mt < 4; ++mt)   // mt = hidden tile (rows=s)
                    #pragma unroll
                    for (int nt = 0; nt < 4; ++nt)  // nt = weight tile (cols=d)
                        acc[mt][nt] = MFMA(af[mt], bb[nt], acc[mt][nt]);
            }
        }
    }

    __syncthreads();                    // As/Bs dead -> Ts reuse safe
    __bf16* Tw = Ts + wid * 4608;      // per-wave 64x72 tile
    const int b  = m0 >> 10;
    const int hq = (nl0 + wn) >> 6;
    const int s_base = (m0 & 1023) + wm;
    const int srow = lane >> 3, c8 = (lane & 7) * 8;

    if (kind < 2) {
        const float* bias = (kind == 0) ? qb : kb;
        __bf16* outp = (kind == 0) ? qo : ko;
        // Tw[s][d], swapped acc: row=d=mt*16+quad*4+r, col=s=nt*16+l16
        #pragma unroll
        for (int mt = 0; mt < 4; ++mt) {
            f32x4 bv = *(const f32x4*)(bias + nl0 + wn + mt * 16 + quad * 4);
            #pragma unroll
            for (int nt = 0; nt < 4; ++nt) {
                bfx4 pk;
                #pragma unroll
                for (int r = 0; r < 4; ++r) pk[r] = (__bf16)(acc[mt][nt][r] + bv[r]);
                *(bfx4*)(Tw + (nt * 16 + l16) * 72 + mt * 16 + quad * 4) = pk;
            }
        }
        __bf16* op = outp + ((((long)(b * NH_ + hq)) << 10) + s_base) * HD_;
        #pragma unroll
        for (int i = 0; i < 8; ++i) {
            bfx8 vv = *(const bfx8*)(Tw + (i * 8 + srow) * 72 + c8);
            *(bfx8*)(op + (i * 8 + srow) * HD_ + c8) = vv;   // 1KB linear/instr
        }
    } else {
        // Tw[d][s], normal acc: row=s=mt*16+quad*4+r, col=d=nt*16+l16
        #pragma unroll
        for (int nt = 0; nt < 4; ++nt) {
            const float bv = vb[nl0 + wn + nt * 16 + l16];
            #pragma unroll
            for (int mt = 0; mt < 4; ++mt) {
                bfx4 pk;
                #pragma unroll
                for (int r = 0; r < 4; ++r) pk[r] = (__bf16)(acc[mt][nt][r] + bv);
                *(bfx4*)(Tw + (nt * 16 + l16) * 72 + mt * 16 + quad * 4) = pk;
            }
        }
        __bf16* op = vto + (((long)(b * NH_ + hq) * HD_) << 10);
        #pragma unroll
        for (int i = 0; i < 8; ++i) {
            const int d = i * 8 + srow;
            bfx8 vv = *(const bfx8*)(Tw + d * 72 + c8);
            *(bfx8*)(op + ((long)d << 10) + s_base + c8) = vv;  // 8 full lines
        }
    }
}

// ---------------------------------------------------------------------------
// Attention, S^T formulation (unchanged from round 4).
// ---------------------------------------------------------------------------
__global__ __launch_bounds__(512, 4) void attn_kernel(
    const __bf16* __restrict__ q, const __bf16* __restrict__ k,
    const __bf16* __restrict__ vT, const float* __restrict__ mask,
    __bf16* __restrict__ ctx)
{
    __shared__ __bf16 Ks[128 * 64];     // 16 KB
    __shared__ __bf16 Vs[64 * 128];     // 16 KB
    __shared__ __bf16 Ps[8][32 * 72];   // 36 KB per-wave [q][key(64)]
    __shared__ float  Ms[1024];         // 4 KB  mask*log2e - SMAX

    const int tid  = threadIdx.x;
    const int lane = tid & 63, wid = tid >> 6;
    const int quad = lane >> 4, l16 = lane & 15;
    const int qc = blockIdx.x, h = blockIdx.y, b = blockIdx.z;

    const long base = ((long)(b * NH_ + h)) << 16;   // * S_ * HD_
    const __bf16* qh = q  + base;
    const __bf16* kh = k  + base;
    const __bf16* vh = vT + base;
    const float*  mb = mask + b * S_;

    Ms[tid]       = mb[tid]       * LOG2E - SMAX;
    Ms[tid + 512] = mb[tid + 512] * LOG2E - SMAX;

    const int qrow_base = qc * 256 + wid * 32;
    bfx8 qf[2][2];
    #pragma unroll
    for (int nt = 0; nt < 2; ++nt)
        #pragma unroll
        for (int ks = 0; ks < 2; ++ks)
            qf[nt][ks] = *(const bfx8*)(qh + (qrow_base + nt * 16 + l16) * HD_ +
                                        ks * 32 + quad * 8);

    f32x4 o[4][2];
    f32x4 lacc[2];
    #pragma unroll
    for (int mt = 0; mt < 4; ++mt)
        #pragma unroll
        for (int nt = 0; nt < 2; ++nt)
            #pragma unroll
            for (int r = 0; r < 4; ++r) o[mt][nt][r] = 0.0f;
    #pragma unroll
    for (int nt = 0; nt < 2; ++nt)
        #pragma unroll
        for (int r = 0; r < 4; ++r) lacc[nt][r] = 0.0f;

    const int krow = lane >> 3;                        // K: 8 keys/chunk
    const int kcol = ((lane & 7) ^ (krow & 7)) * 8;
    const int vrow = lane >> 4;                        // V: 4 d-rows/chunk
    const int swz  = (l16 & 7);

    for (int kt = 0; kt < 8; ++kt) {
        __syncthreads();
        #pragma unroll
        for (int c = 0; c < 2; ++c) {
            const int cc = wid * 2 + c;     // chunk 0..15
            async_cp16(kh + (long)(kt * 128 + cc * 8 + krow) * HD_ + kcol,
                       Ks + cc * 512);
            const int vcol = ((lane & 15) ^ ((c << 2) | vrow)) * 8;
            async_cp16(vh + (long)(cc * 4 + vrow) * S_ + kt * 128 + vcol,
                       Vs + cc * 512);
        }
        __syncthreads();

        #pragma unroll
        for (int kh2 = 0; kh2 < 2; ++kh2) {
            #pragma unroll
            for (int t = 0; t < 4; ++t) {
                f32x4 sc[2];
                #pragma unroll
                for (int nt = 0; nt < 2; ++nt)
                    #pragma unroll
                    for (int r = 0; r < 4; ++r) sc[nt][r] = 0.0f;
                #pragma unroll
                for (int ks = 0; ks < 2; ++ks) {
                    bfx8 kf = *(const bfx8*)(Ks + (kh2 * 64 + t * 16 + l16) * 64 +
                                             ((ks * 4 + quad) ^ swz) * 8);
                    #pragma unroll
                    for (int nt = 0; nt < 2; ++nt)
                        sc[nt] = MFMA(kf, qf[nt][ks], sc[nt]);
                }
                const f32x4 mv = *(const f32x4*)(&Ms[kt * 128 + kh2 * 64 +
                                                    t * 16 + quad * 4]);
                #pragma unroll
                for (int nt = 0; nt < 2; ++nt) {
                    f32x4 p; bfx4 pb;
                    #pragma unroll
                    for (int r = 0; r < 4; ++r)
                        p[r] = fast_exp2(sc[nt][r] * C1 + mv[r]);
                    lacc[nt] += p;
                    #pragma unroll
                    for (int r = 0; r < 4; ++r) pb[r] = (__bf16)p[r];
                    *(bfx4*)(&Ps[wid][(nt * 16 + l16) * 72 + t * 16 + quad * 4]) = pb;
                }
            }
            #pragma unroll
            for (int ks = 0; ks < 2; ++ks) {
                const int koff = ks * 32 + quad * 8;
                bfx8 pf[2];
                #pragma unroll
                for (int nt = 0; nt < 2; ++nt)
                    pf[nt] = *(const bfx8*)(&Ps[wid][(nt * 16 + l16) * 72 + koff]);
                const int vcg = (kh2 * 8 + ks * 4 + quad) ^ swz;
                #pragma unroll
                for (int mt = 0; mt < 4; ++mt) {
                    bfx8 vf = *(const bfx8*)(Vs + (mt * 16 + l16) * 128 + vcg * 8);
                    #pragma unroll
                    for (int nt = 0; nt < 2; ++nt)
                        o[mt][nt] = MFMA(vf, pf[nt], o[mt][nt]);
                }
            }
        }
    }

    float linv[2];
    #pragma unroll
    for (int nt = 0; nt < 2; ++nt) {
        float s = lacc[nt][0] + lacc[nt][1] + lacc[nt][2] + lacc[nt][3];
        s += __shfl_xor(s, 16);
        s += __shfl_xor(s, 32);
        linv[nt] = 1.0f / s;
    }

    #pragma unroll
    for (int nt = 0; nt < 2; ++nt) {
        #pragma unroll
        for (int mt = 0; mt < 4; ++mt) {
            bfx4 ov;
            #pragma unroll
            for (int r = 0; r < 4; ++r)
                ov[r] = (__bf16)(o[mt][nt][r] * linv[nt]);
            const int qrow = qrow_base + nt * 16 + l16;
            *(bfx4*)(ctx + ((long)(b << 10) + qrow) * H_ + h * HD_ +
                     mt * 16 + quad * 4) = ov;
        }
    }
}

// ---------------------------------------------------------------------------
// Output projection + residual, swizzled staging + XCD-chunked block map.
// ---------------------------------------------------------------------------
__global__ __launch_bounds__(256) void out_gemm(
    const __bf16* __restrict__ ctx, const __bf16* __restrict__ wbuf,
    const float* __restrict__ ob, const float* __restrict__ hidden,
    float* __restrict__ xres)
{
    __shared__ __bf16 As[128 * 64];
    __shared__ __bf16 Bs[128 * 64];

    const int bid  = blockIdx.x;
    const int xcd  = bid & 7;
    const int slot = bid >> 3;          // 0..95
    const int xx   = slot >> 4;         // 0..5
    const int yy   = xcd * 16 + (slot & 15);

    const int tid  = threadIdx.x;
    const int lane = tid & 63, wid = tid >> 6;
    const int quad = lane >> 4, l16 = lane & 15;
    const int n0 = xx * 128;
    const int m0 = yy * 128;
    const int wm = (wid >> 1) * 64, wn = (wid & 1) * 64;

    f32x4 acc[4][4];
    #pragma unroll
    for (int i = 0; i < 4; ++i)
        #pragma unroll
        for (int j = 0; j < 4; ++j)
            #pragma unroll
            for (int r = 0; r < 4; ++r) acc[i][j][r] = 0.0f;

    const int drow = lane >> 3;
    const int dcol = ((lane & 7) ^ (drow & 7)) * 8;
    const __bf16* Ag0 = ctx  + (long)(m0 + drow) * H_ + dcol;
    const __bf16* Bg0 = wbuf + (long)(3 * 768 + n0 + drow) * H_ + dcol;
    const int swz = (l16 & 7);

    for (int kt = 0; kt < 12; ++kt) {
        __syncthreads();
        const int k0 = kt * 64;
        #pragma unroll
        for (int c = 0; c < 4; ++c) {
            const int cc = c * 4 + wid;
            async_cp16(Ag0 + (long)cc * 8 * H_ + k0, As + cc * 512);
            async_cp16(Bg0 + (long)cc * 8 * H_ + k0, Bs + cc * 512);
        }
        __syncthreads();
        #pragma unroll
        for (int ks = 0; ks < 2; ++ks) {
            const int coff = ((ks * 4 + quad) ^ swz) * 8;
            bfx8 af[4], bb[4];
            #pragma unroll
            for (int t = 0; t < 4; ++t) {
                af[t] = *(const bfx8*)(As + (wm + t * 16 + l16) * 64 + coff);
                bb[t] = *(const bfx8*)(Bs + (wn + t * 16 + l16) * 64 + coff);
            }
            #pragma unroll
            for (int mt = 0; mt < 4; ++mt)
                #pragma unroll
                for (int nt = 0; nt < 4; ++nt)
                    acc[mt][nt] = MFMA(af[mt], bb[nt], acc[mt][nt]);
        }
    }

    #pragma unroll
    for (int nt = 0; nt < 4; ++nt) {
        const int n = n0 + wn + nt * 16 + l16;
        const float bv = ob[n];
        #pragma unroll
        for (int mt = 0; mt < 4; ++mt) {
            #pragma unroll
            for (int r = 0; r < 4; ++r) {
                const int m = m0 + wm + mt * 16 + quad * 4 + r;
                const long idx = (long)m * H_ + n;
                xres[idx] = acc[mt][nt][r] + bv + hidden[idx];
            }
        }
    }
}

// ---------------------------------------------------------------------------
// LayerNorm over H=768, wave per row
// ---------------------------------------------------------------------------
__global__ __launch_bounds__(256) void ln_kernel(
    const float* __restrict__ xres, const float* __restrict__ gamma,
    const float* __restrict__ beta, float* __restrict__ out)
{
    const int tid = threadIdx.x, lane = tid & 63, wid = tid >> 6;
    const long row = (long)blockIdx.x * 4 + wid;
    const float* xr = xres + row * H_;

    f32x4 xv[3];
    float sum = 0.0f, sumsq = 0.0f;
    #pragma unroll
    for (int c = 0; c < 3; ++c) {
        xv[c] = *(const f32x4*)(xr + c * 256 + lane * 4);
        #pragma unroll
        for (int j = 0; j < 4; ++j) { sum += xv[c][j]; sumsq += xv[c][j] * xv[c][j]; }
    }
    #pragma unroll
    for (int off = 1; off < 64; off <<= 1) {
        sum   += __shfl_xor(sum, off);
        sumsq += __shfl_xor(sumsq, off);
    }
    const float mean = sum * (1.0f / 768.0f);
    const float var  = sumsq * (1.0f / 768.0f) - mean * mean;
    const float rstd = rsqrtf(var + 1e-12f);

    float* orow = out + row * H_;
    #pragma unroll
    for (int c = 0; c < 3; ++c) {
        f32x4 g  = *(const f32x4*)(gamma + c * 256 + lane * 4);
        f32x4 bt = *(const f32x4*)(beta  + c * 256 + lane * 4);
        f32x4 ov;
        #pragma unroll
        for (int j = 0; j < 4; ++j) ov[j] = (xv[c][j] - mean) * rstd * g[j] + bt[j];
        *(f32x4*)(orow + c * 256 + lane * 4) = ov;
    }
}

extern "C" void kernel_launch(void* const* d_in, const int* in_sizes, int n_in,
                              void* d_out, int out_size, void* d_ws, size_t ws_size,
                              hipStream_t stream)
{
    const float* hidden = (const float*)d_in[0];
    const float* mask   = (const float*)d_in[1];
    const float* qw = (const float*)d_in[2];
    const float* qb = (const float*)d_in[3];
    const float* kw = (const float*)d_in[4];
    const float* kb = (const float*)d_in[5];
    const float* vw = (const float*)d_in[6];
    const float* vb = (const float*)d_in[7];
    const float* ow = (const float*)d_in[8];
    const float* ob = (const float*)d_in[9];
    const float* gamma = (const float*)d_in[10];
    const float* beta  = (const float*)d_in[11];
    float* out = (float*)d_out;

    // ws layout (96 MB): [0,24) hbf->ctx alias; [24,48) q; [48,72) k; [72,96) vt
    // xres fp32 aliases [24,72). wbuf bf16 weights live in d_out until ln.
    char* ws = (char*)d_ws;
    const size_t SZB = (size_t)BS_ * H_ * 2;     // 25,165,824 B per bf16 buffer
    __bf16* hbf  = (__bf16*)ws;
    __bf16* qws  = (__bf16*)(ws + SZB);
    __bf16* kws  = (__bf16*)(ws + 2 * SZB);
    __bf16* vtws = (__bf16*)(ws + 3 * SZB);
    __bf16* cws  = hbf;                          // ctx aliases hbf
    float*  xres = (float*)(ws + SZB);           // aliases q,k
    __bf16* wbuf = (__bf16*)d_out;               // scratch inside output buffer

    precast<<<dim3(7296), 256, 0, stream>>>(hidden, qw, kw, vw, ow, hbf, wbuf);
    qkv_gemm<<<dim3(2304), 256, 0, stream>>>(hbf, wbuf, qb, kb, vb,
                                             qws, kws, vtws);
    attn_kernel<<<dim3(4, 12, 16), 512, 0, stream>>>(qws, kws, vtws, mask, cws);
    out_gemm<<<dim3(768), 256, 0, stream>>>(cws, wbuf, ob, hidden, xres);
    ln_kernel<<<dim3(4096), 256, 0, stream>>>(xres, gamma, beta, out);
}

// Round 6
// 317.532 us; speedup vs baseline: 1.7929x; 1.0253x over previous
//
#include <hip/hip_runtime.h>
#include <hip/hip_bf16.h>

#define B_  16
#define S_  1024
#define H_  768
#define NH_ 12
#define HD_ 64
#define BS_ (B_*S_)   // 16384
#define WROWS_ 589824 // 768*768 per weight matrix

typedef __bf16 bfx8 __attribute__((ext_vector_type(8)));
typedef __bf16 bfx4 __attribute__((ext_vector_type(4)));
typedef float  f32x4 __attribute__((ext_vector_type(4)));

#define MFMA(a,b,c) __builtin_amdgcn_mfma_f32_16x16x32_bf16(a,b,c,0,0,0)

__device__ __forceinline__ float fast_exp2(float x) {
#if __has_builtin(__builtin_amdgcn_exp2f)
    return __builtin_amdgcn_exp2f(x);
#else
    return exp2f(x);
#endif
}

// async global->LDS, 16B per lane; LDS dest = wave-uniform base + lane*16
__device__ __forceinline__ void async_cp16(const __bf16* g, __bf16* l) {
    __builtin_amdgcn_global_load_lds(
        (const __attribute__((address_space(1))) unsigned int*)g,
        (__attribute__((address_space(3))) unsigned int*)l,
        16, 0, 0);
}

#define LOG2E 1.4426950408889634f
#define C1    (0.125f * LOG2E)     // score scale folded with log2(e)
#define SMAX  12.0f                // static softmax offset (exp2 domain)

// ---------------------------------------------------------------------------
// Pre-cast: hidden fp32 -> bf16 (hbf), [qw|kw|vw|ow] fp32 -> bf16 (wbuf).
// ---------------------------------------------------------------------------
__global__ __launch_bounds__(256) void precast(
    const float* __restrict__ hidden,
    const float* __restrict__ qw, const float* __restrict__ kw,
    const float* __restrict__ vw, const float* __restrict__ ow,
    __bf16* __restrict__ hbf, __bf16* __restrict__ wbuf)
{
    const int tid = threadIdx.x;
    const int bid = blockIdx.x;
    if (bid < 6144) {
        const long base = ((long)bid * 256 + tid) * 8;
        f32x4 a = *(const f32x4*)(hidden + base);
        f32x4 b = *(const f32x4*)(hidden + base + 4);
        bfx8 o;
        #pragma unroll
        for (int j = 0; j < 4; ++j) { o[j] = (__bf16)a[j]; o[4 + j] = (__bf16)b[j]; }
        *(bfx8*)(hbf + base) = o;
    } else {
        const long e = ((long)(bid - 6144) * 256 + tid) * 8;
        const int kind = (int)(e / WROWS_);
        const float* src = kind == 0 ? qw : kind == 1 ? kw : kind == 2 ? vw : ow;
        const long off = e - (long)kind * WROWS_;
        f32x4 a = *(const f32x4*)(src + off);
        f32x4 b = *(const f32x4*)(src + off + 4);
        bfx8 o;
        #pragma unroll
        for (int j = 0; j < 4; ++j) { o[j] = (__bf16)a[j]; o[4 + j] = (__bf16)b[j]; }
        *(bfx8*)(wbuf + e) = o;
    }
}

// ---------------------------------------------------------------------------
// Fused QKV GEMM. 128x128 tile, BK=64, swizzled global_load_lds staging.
// 8 waves x (32s x 64d) wave-tile: 32 AGPR acc + ~90 VGPR -> 4 waves/SIMD
// (launch_bounds(512,4)) so DMA barrier drains overlap across blocks.
// XCD-chunked block map keeps one XCD's A-panels in its private L2.
// Q/K: swapped MFMA operands (A=weight) -> acc r spans d -> LDS transpose
// tile -> fully-linear bfx8 global stores. V: normal order (r spans s).
// ---------------------------------------------------------------------------
__global__ __launch_bounds__(512, 4) void qkv_gemm(
    const __bf16* __restrict__ hbf, const __bf16* __restrict__ wbuf,
    const float* __restrict__ qb, const float* __restrict__ kb,
    const float* __restrict__ vb,
    __bf16* __restrict__ qo, __bf16* __restrict__ ko, __bf16* __restrict__ vto)
{
    __shared__ __bf16 smem[18432];      // 36864 B: As|Bs in [0,16384), Ts all
    __bf16* As = smem;                  // 8192 elems
    __bf16* Bs = smem + 8192;           // 8192 elems
    __bf16* Ts = smem;                  // epilogue: 8 waves x 2304 elems

    const int bid  = blockIdx.x;
    const int xcd  = bid & 7;
    const int slot = bid >> 3;          // 0..287
    const int xx   = slot >> 4;         // 0..17  (n-tile / weight panel)
    const int yy   = xcd * 16 + (slot & 15);   // 0..127 (m-tile)

    const int tid  = threadIdx.x;
    const int lane = tid & 63, wid = tid >> 6;
    const int quad = lane >> 4, l16 = lane & 15;
    const int n0g = xx * 128;
    const int m0  = yy * 128;
    const int wm = (wid & 3) * 32;      // s-slice (4)
    const int wn = (wid >> 2) * 64;     // d-slice (2)
    const int kind = xx / 6;            // 0=Q,1=K,2=V
    const int nl0  = n0g - kind * 768;

    // acc: Q/K -> [dt][st] flat dt*2+st ; V -> [st][dt] flat st*4+dt
    f32x4 acc[8];
    #pragma unroll
    for (int i = 0; i < 8; ++i)
        #pragma unroll
        for (int r = 0; r < 4; ++r) acc[i][r] = 0.0f;

    const int drow = lane >> 3;
    const int dcol = ((lane & 7) ^ (drow & 7)) * 8;
    const __bf16* Ag0 = hbf  + (long)(m0  + drow) * H_ + dcol;
    const __bf16* Bg0 = wbuf + (long)(n0g + drow) * H_ + dcol;
    const int swz = (l16 & 7);

    for (int kt = 0; kt < 12; ++kt) {
        __syncthreads();
        const int k0 = kt * 64;
        #pragma unroll
        for (int c = 0; c < 2; ++c) {
            const int cc = wid * 2 + c;       // chunk 0..15 (8 rows each)
            async_cp16(Ag0 + (long)cc * 8 * H_ + k0, As + cc * 512);
            async_cp16(Bg0 + (long)cc * 8 * H_ + k0, Bs + cc * 512);
        }
        __syncthreads();
        #pragma unroll
        for (int ks = 0; ks < 2; ++ks) {
            const int coff = ((ks * 4 + quad) ^ swz) * 8;
            bfx8 af[2], bb[4];
            #pragma unroll
            for (int t = 0; t < 2; ++t)
                af[t] = *(const bfx8*)(As + (wm + t * 16 + l16) * 64 + coff);
            #pragma unroll
            for (int t = 0; t < 4; ++t)
                bb[t] = *(const bfx8*)(Bs + (wn + t * 16 + l16) * 64 + coff);
            if (kind < 2) {
                #pragma unroll
                for (int dt = 0; dt < 4; ++dt)
                    #pragma unroll
                    for (int st = 0; st < 2; ++st)
                        acc[dt * 2 + st] = MFMA(bb[dt], af[st], acc[dt * 2 + st]);
            } else {
                #pragma unroll
                for (int st = 0; st < 2; ++st)
                    #pragma unroll
                    for (int dt = 0; dt < 4; ++dt)
                        acc[st * 4 + dt] = MFMA(af[st], bb[dt], acc[st * 4 + dt]);
            }
        }
    }

    __syncthreads();                    // As/Bs dead -> Ts reuse safe
    const int b  = m0 >> 10;
    const int hq = (nl0 + wn) >> 6;
    const int s_base = (m0 & 1023) + wm;

    if (kind < 2) {
        __bf16* Tw = Ts + wid * 2304;   // 32 x 72 tile [s][d]
        const float* bias = (kind == 0) ? qb : kb;
        __bf16* outp = (kind == 0) ? qo : ko;
        // acc[dt*2+st]: row=d=dt*16+quad*4+r, col=s=st*16+l16
        #pragma unroll
        for (int dt = 0; dt < 4; ++dt) {
            f32x4 bv = *(const f32x4*)(bias + nl0 + wn + dt * 16 + quad * 4);
            #pragma unroll
            for (int st = 0; st < 2; ++st) {
                bfx4 pk;
                #pragma unroll
                for (int r = 0; r < 4; ++r)
                    pk[r] = (__bf16)(acc[dt * 2 + st][r] + bv[r]);
                *(bfx4*)(Tw + (st * 16 + l16) * 72 + dt * 16 + quad * 4) = pk;
            }
        }
        __bf16* op = outp + ((((long)(b * NH_ + hq)) << 10) + s_base) * HD_;
        const int srow = lane >> 3, c8 = (lane & 7) * 8;
        #pragma unroll
        for (int i = 0; i < 4; ++i) {
            const int row = i * 8 + srow;                     // 0..31
            bfx8 vv = *(const bfx8*)(Tw + row * 72 + c8);
            *(bfx8*)(op + row * HD_ + c8) = vv;               // 1KB linear/instr
        }
    } else {
        __bf16* Tw = Ts + wid * 2304;   // 64 x 36 tile [d][s]
        // acc[st*4+dt]: row=s=st*16+quad*4+r, col=d=dt*16+l16
        #pragma unroll
        for (int dt = 0; dt < 4; ++dt) {
            const float bv = vb[nl0 + wn + dt * 16 + l16];
            #pragma unroll
            for (int st = 0; st < 2; ++st) {
                bfx4 pk;
                #pragma unroll
                for (int r = 0; r < 4; ++r)
                    pk[r] = (__bf16)(acc[st * 4 + dt][r] + bv);
                *(bfx4*)(Tw + (dt * 16 + l16) * 36 + st * 16 + quad * 4) = pk;
            }
        }
        __bf16* op = vto + (((long)(b * NH_ + hq) * HD_) << 10);
        #pragma unroll
        for (int i = 0; i < 4; ++i) {
            const int d = i * 16 + (lane >> 2);
            const int s8 = (lane & 3) * 8;
            bfx8 vv = *(const bfx8*)(Tw + d * 36 + s8);
            *(bfx8*)(op + ((long)d << 10) + s_base + s8) = vv;
        }
    }
}

// ---------------------------------------------------------------------------
// Attention, S^T formulation (unchanged from round 5).
// ---------------------------------------------------------------------------
__global__ __launch_bounds__(512, 4) void attn_kernel(
    const __bf16* __restrict__ q, const __bf16* __restrict__ k,
    const __bf16* __restrict__ vT, const float* __restrict__ mask,
    __bf16* __restrict__ ctx)
{
    __shared__ __bf16 Ks[128 * 64];     // 16 KB
    __shared__ __bf16 Vs[64 * 128];     // 16 KB
    __shared__ __bf16 Ps[8][32 * 72];   // 36 KB per-wave [q][key(64)]
    __shared__ float  Ms[1024];         // 4 KB  mask*log2e - SMAX

    const int tid  = threadIdx.x;
    const int lane = tid & 63, wid = tid >> 6;
    const int quad = lane >> 4, l16 = lane & 15;
    const int qc = blockIdx.x, h = blockIdx.y, b = blockIdx.z;

    const long base = ((long)(b * NH_ + h)) << 16;   // * S_ * HD_
    const __bf16* qh = q  + base;
    const __bf16* kh = k  + base;
    const __bf16* vh = vT + base;
    const float*  mb = mask + b * S_;

    Ms[tid]       = mb[tid]       * LOG2E - SMAX;
    Ms[tid + 512] = mb[tid + 512] * LOG2E - SMAX;

    const int qrow_base = qc * 256 + wid * 32;
    bfx8 qf[2][2];
    #pragma unroll
    for (int nt = 0; nt < 2; ++nt)
        #pragma unroll
        for (int ks = 0; ks < 2; ++ks)
            qf[nt][ks] = *(const bfx8*)(qh + (qrow_base + nt * 16 + l16) * HD_ +
                                        ks * 32 + quad * 8);

    f32x4 o[4][2];
    f32x4 lacc[2];
    #pragma unroll
    for (int mt = 0; mt < 4; ++mt)
        #pragma unroll
        for (int nt = 0; nt < 2; ++nt)
            #pragma unroll
            for (int r = 0; r < 4; ++r) o[mt][nt][r] = 0.0f;
    #pragma unroll
    for (int nt = 0; nt < 2; ++nt)
        #pragma unroll
        for (int r = 0; r < 4; ++r) lacc[nt][r] = 0.0f;

    const int krow = lane >> 3;                        // K: 8 keys/chunk
    const int kcol = ((lane & 7) ^ (krow & 7)) * 8;
    const int vrow = lane >> 4;                        // V: 4 d-rows/chunk
    const int swz  = (l16 & 7);

    for (int kt = 0; kt < 8; ++kt) {
        __syncthreads();
        #pragma unroll
        for (int c = 0; c < 2; ++c) {
            const int cc = wid * 2 + c;     // chunk 0..15
            async_cp16(kh + (long)(kt * 128 + cc * 8 + krow) * HD_ + kcol,
                       Ks + cc * 512);
            const int vcol = ((lane & 15) ^ ((c << 2) | vrow)) * 8;
            async_cp16(vh + (long)(cc * 4 + vrow) * S_ + kt * 128 + vcol,
                       Vs + cc * 512);
        }
        __syncthreads();

        #pragma unroll
        for (int kh2 = 0; kh2 < 2; ++kh2) {
            #pragma unroll
            for (int t = 0; t < 4; ++t) {
                f32x4 sc[2];
                #pragma unroll
                for (int nt = 0; nt < 2; ++nt)
                    #pragma unroll
                    for (int r = 0; r < 4; ++r) sc[nt][r] = 0.0f;
                #pragma unroll
                for (int ks = 0; ks < 2; ++ks) {
                    bfx8 kf = *(const bfx8*)(Ks + (kh2 * 64 + t * 16 + l16) * 64 +
                                             ((ks * 4 + quad) ^ swz) * 8);
                    #pragma unroll
                    for (int nt = 0; nt < 2; ++nt)
                        sc[nt] = MFMA(kf, qf[nt][ks], sc[nt]);
                }
                const f32x4 mv = *(const f32x4*)(&Ms[kt * 128 + kh2 * 64 +
                                                    t * 16 + quad * 4]);
                #pragma unroll
                for (int nt = 0; nt < 2; ++nt) {
                    f32x4 p; bfx4 pb;
                    #pragma unroll
                    for (int r = 0; r < 4; ++r)
                        p[r] = fast_exp2(sc[nt][r] * C1 + mv[r]);
                    lacc[nt] += p;
                    #pragma unroll
                    for (int r = 0; r < 4; ++r) pb[r] = (__bf16)p[r];
                    *(bfx4*)(&Ps[wid][(nt * 16 + l16) * 72 + t * 16 + quad * 4]) = pb;
                }
            }
            #pragma unroll
            for (int ks = 0; ks < 2; ++ks) {
                const int koff = ks * 32 + quad * 8;
                bfx8 pf[2];
                #pragma unroll
                for (int nt = 0; nt < 2; ++nt)
                    pf[nt] = *(const bfx8*)(&Ps[wid][(nt * 16 + l16) * 72 + koff]);
                const int vcg = (kh2 * 8 + ks * 4 + quad) ^ swz;
                #pragma unroll
                for (int mt = 0; mt < 4; ++mt) {
                    bfx8 vf = *(const bfx8*)(Vs + (mt * 16 + l16) * 128 + vcg * 8);
                    #pragma unroll
                    for (int nt = 0; nt < 2; ++nt)
                        o[mt][nt] = MFMA(vf, pf[nt], o[mt][nt]);
                }
            }
        }
    }

    float linv[2];
    #pragma unroll
    for (int nt = 0; nt < 2; ++nt) {
        float s = lacc[nt][0] + lacc[nt][1] + lacc[nt][2] + lacc[nt][3];
        s += __shfl_xor(s, 16);
        s += __shfl_xor(s, 32);
        linv[nt] = 1.0f / s;
    }

    #pragma unroll
    for (int nt = 0; nt < 2; ++nt) {
        #pragma unroll
        for (int mt = 0; mt < 4; ++mt) {
            bfx4 ov;
            #pragma unroll
            for (int r = 0; r < 4; ++r)
                ov[r] = (__bf16)(o[mt][nt][r] * linv[nt]);
            const int qrow = qrow_base + nt * 16 + l16;
            *(bfx4*)(ctx + ((long)(b << 10) + qrow) * H_ + h * HD_ +
                     mt * 16 + quad * 4) = ov;
        }
    }
}

// ---------------------------------------------------------------------------
// Output projection + residual. 8 waves x (32m x 64n), XCD-chunked map.
// ---------------------------------------------------------------------------
__global__ __launch_bounds__(512, 4) void out_gemm(
    const __bf16* __restrict__ ctx, const __bf16* __restrict__ wbuf,
    const float* __restrict__ ob, const float* __restrict__ hidden,
    float* __restrict__ xres)
{
    __shared__ __bf16 As[128 * 64];
    __shared__ __bf16 Bs[128 * 64];

    const int bid  = blockIdx.x;
    const int xcd  = bid & 7;
    const int slot = bid >> 3;          // 0..95
    const int xx   = slot >> 4;         // 0..5
    const int yy   = xcd * 16 + (slot & 15);

    const int tid  = threadIdx.x;
    const int lane = tid & 63, wid = tid >> 6;
    const int quad = lane >> 4, l16 = lane & 15;
    const int n0 = xx * 128;
    const int m0 = yy * 128;
    const int wm = (wid & 3) * 32;
    const int wn = (wid >> 2) * 64;

    f32x4 acc[2][4];
    #pragma unroll
    for (int i = 0; i < 2; ++i)
        #pragma unroll
        for (int j = 0; j < 4; ++j)
            #pragma unroll
            for (int r = 0; r < 4; ++r) acc[i][j][r] = 0.0f;

    const int drow = lane >> 3;
    const int dcol = ((lane & 7) ^ (drow & 7)) * 8;
    const __bf16* Ag0 = ctx  + (long)(m0 + drow) * H_ + dcol;
    const __bf16* Bg0 = wbuf + (long)(3 * 768 + n0 + drow) * H_ + dcol;
    const int swz = (l16 & 7);

    for (int kt = 0; kt < 12; ++kt) {
        __syncthreads();
        const int k0 = kt * 64;
        #pragma unroll
        for (int c = 0; c < 2; ++c) {
            const int cc = wid * 2 + c;
            async_cp16(Ag0 + (long)cc * 8 * H_ + k0, As + cc * 512);
            async_cp16(Bg0 + (long)cc * 8 * H_ + k0, Bs + cc * 512);
        }
        __syncthreads();
        #pragma unroll
        for (int ks = 0; ks < 2; ++ks) {
            const int coff = ((ks * 4 + quad) ^ swz) * 8;
            bfx8 af[2], bb[4];
            #pragma unroll
            for (int t = 0; t < 2; ++t)
                af[t] = *(const bfx8*)(As + (wm + t * 16 + l16) * 64 + coff);
            #pragma unroll
            for (int t = 0; t < 4; ++t)
                bb[t] = *(const bfx8*)(Bs + (wn + t * 16 + l16) * 64 + coff);
            #pragma unroll
            for (int mt = 0; mt < 2; ++mt)
                #pragma unroll
                for (int nt = 0; nt < 4; ++nt)
                    acc[mt][nt] = MFMA(af[mt], bb[nt], acc[mt][nt]);
        }
    }

    #pragma unroll
    for (int nt = 0; nt < 4; ++nt) {
        const int n = n0 + wn + nt * 16 + l16;
        const float bv = ob[n];
        #pragma unroll
        for (int mt = 0; mt < 2; ++mt) {
            #pragma unroll
            for (int r = 0; r < 4; ++r) {
                const int m = m0 + wm + mt * 16 + quad * 4 + r;
                const long idx = (long)m * H_ + n;
                xres[idx] = acc[mt][nt][r] + bv + hidden[idx];
            }
        }
    }
}

// ---------------------------------------------------------------------------
// LayerNorm over H=768, wave per row
// ---------------------------------------------------------------------------
__global__ __launch_bounds__(256) void ln_kernel(
    const float* __restrict__ xres, const float* __restrict__ gamma,
    const float* __restrict__ beta, float* __restrict__ out)
{
    const int tid = threadIdx.x, lane = tid & 63, wid = tid >> 6;
    const long row = (long)blockIdx.x * 4 + wid;
    const float* xr = xres + row * H_;

    f32x4 xv[3];
    float sum = 0.0f, sumsq = 0.0f;
    #pragma unroll
    for (int c = 0; c < 3; ++c) {
        xv[c] = *(const f32x4*)(xr + c * 256 + lane * 4);
        #pragma unroll
        for (int j = 0; j < 4; ++j) { sum += xv[c][j]; sumsq += xv[c][j] * xv[c][j]; }
    }
    #pragma unroll
    for (int off = 1; off < 64; off <<= 1) {
        sum   += __shfl_xor(sum, off);
        sumsq += __shfl_xor(sumsq, off);
    }
    const float mean = sum * (1.0f / 768.0f);
    const float var  = sumsq * (1.0f / 768.0f) - mean * mean;
    const float rstd = rsqrtf(var + 1e-12f);

    float* orow = out + row * H_;
    #pragma unroll
    for (int c = 0; c < 3; ++c) {
        f32x4 g  = *(const f32x4*)(gamma + c * 256 + lane * 4);
        f32x4 bt = *(const f32x4*)(beta  + c * 256 + lane * 4);
        f32x4 ov;
        #pragma unroll
        for (int j = 0; j < 4; ++j) ov[j] = (xv[c][j] - mean) * rstd * g[j] + bt[j];
        *(f32x4*)(orow + c * 256 + lane * 4) = ov;
    }
}

extern "C" void kernel_launch(void* const* d_in, const int* in_sizes, int n_in,
                              void* d_out, int out_size, void* d_ws, size_t ws_size,
                              hipStream_t stream)
{
    const float* hidden = (const float*)d_in[0];
    const float* mask   = (const float*)d_in[1];
    const float* qw = (const float*)d_in[2];
    const float* qb = (const float*)d_in[3];
    const float* kw = (const float*)d_in[4];
    const float* kb = (const float*)d_in[5];
    const float* vw = (const float*)d_in[6];
    const float* vb = (const float*)d_in[7];
    const float* ow = (const float*)d_in[8];
    const float* ob = (const float*)d_in[9];
    const float* gamma = (const float*)d_in[10];
    const float* beta  = (const float*)d_in[11];
    float* out = (float*)d_out;

    // ws layout (96 MB): [0,24) hbf->ctx alias; [24,48) q; [48,72) k; [72,96) vt
    // xres fp32 aliases [24,72). wbuf bf16 weights live in d_out until ln.
    char* ws = (char*)d_ws;
    const size_t SZB = (size_t)BS_ * H_ * 2;     // 25,165,824 B per bf16 buffer
    __bf16* hbf  = (__bf16*)ws;
    __bf16* qws  = (__bf16*)(ws + SZB);
    __bf16* kws  = (__bf16*)(ws + 2 * SZB);
    __bf16* vtws = (__bf16*)(ws + 3 * SZB);
    __bf16* cws  = hbf;                          // ctx aliases hbf
    float*  xres = (float*)(ws + SZB);           // aliases q,k
    __bf16* wbuf = (__bf16*)d_out;               // scratch inside output buffer

    precast<<<dim3(7296), 256, 0, stream>>>(hidden, qw, kw, vw, ow, hbf, wbuf);
    qkv_gemm<<<dim3(2304), 512, 0, stream>>>(hbf, wbuf, qb, kb, vb,
                                             qws, kws, vtws);
    attn_kernel<<<dim3(4, 12, 16), 512, 0, stream>>>(qws, kws, vtws, mask, cws);
    out_gemm<<<dim3(768), 512, 0, stream>>>(cws, wbuf, ob, hidden, xres);
    ln_kernel<<<dim3(4096), 256, 0, stream>>>(xres, gamma, beta, out);
}